// Round 15
// baseline (165614.978 us; speedup 1.0000x reference)
//
#include <hip/hip_runtime.h>
#include <hip/hip_fp16.h>

// Problem sizes
static constexpr int NB = 1024;   // batch
static constexpr int NS = 200;    // seq len
static constexpr int NH = 256;    // hidden == embed
static constexpr int NG4 = 1024;  // 4*H

#define NEG_INF (-__builtin_inff())
static constexpr float LOG2E = 1.4426950408889634f;
static constexpr float LN2   = 0.6931471805599453f;

// ---------------- workspace layout (float offsets) ----------------
static constexpr size_t OFF_EGS   = 0;                                    // fp8 [B][200][256]
static constexpr size_t OFF_EPS   = OFF_EGS  + (size_t)NB*NS*NH/4;        // fp8 [B][200][256]
static constexpr size_t OFF_EMBP  = OFF_EPS  + (size_t)NB*NS*NH/4;        // fp8 [S][B][1024] emb@WihT
static constexpr size_t OFF_M     = OFF_EMBP + (size_t)NS*NB*NG4/4;       // fp8 [B][200][256] eg@WqpT
static constexpr size_t OFF_WIHT  = OFF_M    + (size_t)NB*NS*NH/4;        // f32 [256][1024] gate-interleaved
static constexpr size_t OFF_WHHT  = OFF_WIHT + (size_t)NH*NG4;            // f32 [256][1024]
static constexpr size_t OFF_BSUM  = OFF_WHHT + (size_t)NH*NG4;            // f32 [1024]
static constexpr size_t OFF_WQG2  = OFF_BSUM + 1024;                      // half2-packed WqTg [128][256]
static constexpr size_t OFF_WQTP  = OFF_WQG2 + (size_t)128*256;           // f32 (unused by decode now)
static constexpr size_t OFF_WRTG  = OFF_WQTP + (size_t)NH*NH;
static constexpr size_t OFF_WRTP  = OFF_WRTG + (size_t)NH*NH;
static constexpr size_t OFF_H     = OFF_WRTP + (size_t)NH*NH;             // f32 [B][256]
static constexpr size_t OFF_C0    = OFF_H    + (size_t)NB*NH;             // c parity
static constexpr size_t OFF_C1    = OFF_C0   + (size_t)NB*NH;
static constexpr size_t OFF_DECP0 = OFF_C1   + (size_t)NB*NH;             // decp parity [B][1024]
static constexpr size_t OFF_DECP1 = OFF_DECP0 + (size_t)NB*NG4;
static constexpr size_t OFF_WHB0  = OFF_DECP1 + (size_t)NB*NG4;           // whb parity [B][1024]
static constexpr size_t OFF_WHB1  = OFF_WHB0 + (size_t)NB*NG4;
static constexpr size_t OFF_BAR   = OFF_WHB1 + (size_t)NB*NG4;            // barrier: 64*32 + 8*32 + 2 uints
// bf16x8-packed B fragments
static constexpr size_t OFF_BPK_IH = OFF_BAR + 4096;                      // [32][1024] x 16B
static constexpr size_t OFF_BPK_RG = OFF_BPK_IH + (size_t)32*1024*4;      // [32][256] x 16B
static constexpr size_t OFF_BPK_RP = OFF_BPK_RG + (size_t)32*256*4;
static constexpr size_t OFF_BPK_QP = OFF_BPK_RP + (size_t)32*256*4;

// ---------------- output layout (float offsets) ----------------
static constexpr size_t OUT_SELS = (size_t)NB*NS*NS;   // log_p first
static constexpr size_t OUT_H    = OUT_SELS + (size_t)NB*NS;
static constexpr size_t OUT_C    = OUT_H + (size_t)NB*NH;

// ---------------- types / fast math ----------------
typedef float f32x2 __attribute__((ext_vector_type(2)));
typedef float f32x4 __attribute__((ext_vector_type(4)));
typedef short bf16x8 __attribute__((ext_vector_type(8)));   // 8 bf16 in 4 VGPRs

__device__ __forceinline__ float fast_exp2(float x) {
  float d; asm("v_exp_f32 %0, %1" : "=v"(d) : "v"(x)); return d;
}
__device__ __forceinline__ float fast_rcp(float x) {
  float d; asm("v_rcp_f32 %0, %1" : "=v"(d) : "v"(x)); return d;
}
__device__ __forceinline__ float fast_log2(float x) {
  float d; asm("v_log_f32 %0, %1" : "=v"(d) : "v"(x)); return d;
}
__device__ __forceinline__ float fast_tanh(float x) {
  float e = fast_exp2(x * (2.0f * LOG2E));
  return fmaf(-2.0f, fast_rcp(e + 1.0f), 1.0f);
}
__device__ __forceinline__ float fast_sigm(float x) {
  float e = fast_exp2(x * (-LOG2E));
  return fast_rcp(1.0f + e);
}
__device__ __forceinline__ float fast_expn(float a) {   // exp(a), a<=0 (or -inf -> 0)
  return fast_exp2(a * LOG2E);
}
__device__ __forceinline__ f32x2 cvt2_fp8(unsigned int u) {
  f32x2 d; asm("v_cvt_pk_f32_fp8 %0, %1" : "=v"(d) : "v"(u)); return d;
}
__device__ __forceinline__ unsigned int f32_to_e4m3(float x) {
  x = fminf(fmaxf(x, -448.0f), 448.0f);
  unsigned int u = __float_as_uint(x);
  unsigned int s = (u >> 24) & 0x80u;
  unsigned int au = u & 0x7fffffffu;
  if (au < 0x3c800000u) return s;
  unsigned int r = au + 0x7ffffu + ((au >> 20) & 1u);
  unsigned int expf8 = (r >> 23) - 120u;
  unsigned int man = (r >> 20) & 7u;
  return s | (expf8 << 3) | man;
}
// f32 -> bf16 (RNE)
__device__ __forceinline__ unsigned f32_bf16(float x) {
  unsigned u = __float_as_uint(x);
  unsigned r = u + 0x7fffu + ((u >> 16) & 1u);
  return r >> 16;
}

// ---------------- init: weight transforms + bf16 fragment packing + barrier clear ------
__global__ __launch_bounds__(256) void k_init(
    const float* __restrict__ h0, const float* __restrict__ c0,
    const float* __restrict__ W_ih, const float* __restrict__ W_hh,
    const float* __restrict__ b_ih, const float* __restrict__ b_hh,
    const float* __restrict__ Wq_g, const float* __restrict__ Wq_p,
    const float* __restrict__ Wref_g, const float* __restrict__ Wref_p,
    float* __restrict__ ws)
{
  const int i0 = blockIdx.x * 256 + threadIdx.x;
  const int stride = gridDim.x * 256;
  float* WIHT = ws + OFF_WIHT;
  float* WHHT = ws + OFF_WHHT;
  float* BS   = ws + OFF_BSUM;
  unsigned* WQG2 = (unsigned*)(ws + OFF_WQG2);
  // gate-interleaved col j = h*4+g  -> source row = g*256+h
  for (int t = i0; t < NH * NG4; t += stride) {
    int k = t >> 10, j = t & 1023;
    int row = (j & 3) * 256 + (j >> 2);
    WIHT[t] = W_ih[row * NH + k];
    WHHT[t] = W_hh[row * NH + k];
  }
  for (int t = i0; t < 1024; t += stride) {
    int row = (t & 3) * 256 + (t >> 2);
    BS[t] = b_ih[row] + b_hh[row];
  }
  for (int t = i0; t < 128 * 256; t += stride) {
    int kk = t >> 8, o = t & 255;
    __half lo = __float2half(Wq_g[o * NH + 2 * kk]);
    __half hi = __float2half(Wq_g[o * NH + 2 * kk + 1]);
    unsigned v = ((unsigned)__half_as_ushort(hi) << 16) | (unsigned)__half_as_ushort(lo);
    WQG2[t] = v;
  }
  // bf16x8 fragment packs
  {
    uint4* BP = (uint4*)(ws + OFF_BPK_IH);
    for (int t = i0; t < 32 * 1024; t += stride) {
      int kg = t >> 10, n = t & 1023;
      int row = (n & 3) * 256 + (n >> 2);
      unsigned us[8];
#pragma unroll
      for (int j = 0; j < 8; ++j) us[j] = f32_bf16(W_ih[row * NH + kg * 8 + j]) & 0xffffu;
      BP[t] = (uint4){ us[0]|(us[1]<<16), us[2]|(us[3]<<16), us[4]|(us[5]<<16), us[6]|(us[7]<<16) };
    }
  }
  {
    uint4* BG = (uint4*)(ws + OFF_BPK_RG);
    uint4* BR = (uint4*)(ws + OFF_BPK_RP);
    uint4* BQ = (uint4*)(ws + OFF_BPK_QP);
    for (int t = i0; t < 32 * 256; t += stride) {
      int kg = t >> 8, n = t & 255;
      unsigned g[8], r[8], q[8];
#pragma unroll
      for (int j = 0; j < 8; ++j) {
        int k = kg * 8 + j;
        g[j] = f32_bf16(Wref_g[n * NH + k]) & 0xffffu;
        r[j] = f32_bf16(Wref_p[n * NH + k]) & 0xffffu;
        q[j] = f32_bf16(Wq_p[n * NH + k]) & 0xffffu;
      }
      BG[t] = (uint4){ g[0]|(g[1]<<16), g[2]|(g[3]<<16), g[4]|(g[5]<<16), g[6]|(g[7]<<16) };
      BR[t] = (uint4){ r[0]|(r[1]<<16), r[2]|(r[3]<<16), r[4]|(r[5]<<16), r[6]|(r[7]<<16) };
      BQ[t] = (uint4){ q[0]|(q[1]<<16), q[2]|(q[3]<<16), q[4]|(q[5]<<16), q[6]|(q[7]<<16) };
    }
  }
  float* hbuf = ws + OFF_H;
  float* cbuf = ws + OFF_C0;
  for (int t = i0; t < NB * NH; t += stride) {
    hbuf[t] = h0[t]; cbuf[t] = c0[t];
  }
  unsigned* bar = (unsigned*)(ws + OFF_BAR);
  for (int t = i0; t < 64 * 32 + 8 * 32 + 2; t += stride) bar[t] = 0u;
}

// ---------------- MFMA helpers ----------------
__device__ __forceinline__ bf16x8 load_a_bf16(const float* ap) {
  float4 a0 = *(const float4*)ap;
  float4 a1 = *(const float4*)(ap + 4);
  bf16x8 af;
  af[0] = (short)f32_bf16(a0.x); af[1] = (short)f32_bf16(a0.y);
  af[2] = (short)f32_bf16(a0.z); af[3] = (short)f32_bf16(a0.w);
  af[4] = (short)f32_bf16(a1.x); af[5] = (short)f32_bf16(a1.y);
  af[6] = (short)f32_bf16(a1.z); af[7] = (short)f32_bf16(a1.w);
  return af;
}

// ---------------- embproj (MFMA): [204800][256]f32 @ B[256][1024] -> fp8 ----------------
__global__ __launch_bounds__(256) void k_embproj_mfma(
    const float* __restrict__ A, const bf16x8* __restrict__ Bpk,
    unsigned char* __restrict__ C)
{
  __shared__ float Ct[64][132];
  const int tid = threadIdx.x, l = tid & 63, w = tid >> 6;
  const int r0 = blockIdx.y * 64, n0 = blockIdx.x * 128;
  const int arow = r0 + w * 16 + (l & 15);
  const int kg0 = l >> 4;
  f32x4 acc[8] = {};
  for (int kc = 0; kc < 8; ++kc) {
    bf16x8 af = load_a_bf16(A + (size_t)arow * 256 + kc * 32 + kg0 * 8);
    const bf16x8* bp = Bpk + (size_t)(kc * 4 + kg0) * 1024 + n0 + (l & 15);
#pragma unroll
    for (int ct = 0; ct < 8; ++ct)
      acc[ct] = __builtin_amdgcn_mfma_f32_16x16x32_bf16(af, bp[ct * 16], acc[ct], 0, 0, 0);
  }
#pragma unroll
  for (int ct = 0; ct < 8; ++ct)
#pragma unroll
    for (int r = 0; r < 4; ++r)
      Ct[w * 16 + (l >> 4) * 4 + r][ct * 16 + (l & 15)] = acc[ct][r];
  __syncthreads();
  const int lr = tid >> 2, u0 = (tid & 3) * 8;
  size_t base = (size_t)(r0 + lr) * 1024 + n0;
#pragma unroll
  for (int i = 0; i < 8; ++i) {
    int cb = (u0 + i) * 4;
    unsigned pk = f32_to_e4m3(Ct[lr][cb])        | (f32_to_e4m3(Ct[lr][cb + 1]) << 8)
                | (f32_to_e4m3(Ct[lr][cb + 2]) << 16) | (f32_to_e4m3(Ct[lr][cb + 3]) << 24);
    *(unsigned*)(C + base + cb) = pk;
  }
}

// ---------------- eproj (MFMA) ----------------
__global__ __launch_bounds__(256) void k_eproj_mfma(
    const float* __restrict__ A, const bf16x8* __restrict__ Bpk,
    const float* __restrict__ bias, unsigned char* __restrict__ C)
{
  __shared__ float Ct[64][132];
  const int tid = threadIdx.x, l = tid & 63, w = tid >> 6;
  const int r0 = blockIdx.y * 64, n0 = blockIdx.x * 128;
  const int arow = r0 + w * 16 + (l & 15);
  const int kg0 = l >> 4;
  f32x4 acc[8] = {};
  for (int kc = 0; kc < 8; ++kc) {
    bf16x8 af = load_a_bf16(A + (size_t)arow * 256 + kc * 32 + kg0 * 8);
    const bf16x8* bp = Bpk + (size_t)(kc * 4 + kg0) * 256 + n0 + (l & 15);
#pragma unroll
    for (int ct = 0; ct < 8; ++ct)
      acc[ct] = __builtin_amdgcn_mfma_f32_16x16x32_bf16(af, bp[ct * 16], acc[ct], 0, 0, 0);
  }
#pragma unroll
  for (int ct = 0; ct < 8; ++ct)
#pragma unroll
    for (int r = 0; r < 4; ++r)
      Ct[w * 16 + (l >> 4) * 4 + r][ct * 16 + (l & 15)] = acc[ct][r];
  __syncthreads();
  const int lr = tid >> 2, u0 = (tid & 3) * 8;
  const int R = r0 + lr;
  const int b = R & 1023, s = R >> 10;
  size_t base = (size_t)b * (NS * NH) + (size_t)s * NH + n0;
#pragma unroll
  for (int i = 0; i < 8; ++i) {
    int cb = (u0 + i) * 4;
    unsigned pk = f32_to_e4m3(Ct[lr][cb] + bias[n0 + cb])
                | (f32_to_e4m3(Ct[lr][cb + 1] + bias[n0 + cb + 1]) << 8)
                | (f32_to_e4m3(Ct[lr][cb + 2] + bias[n0 + cb + 2]) << 16)
                | (f32_to_e4m3(Ct[lr][cb + 3] + bias[n0 + cb + 3]) << 24);
    *(unsigned*)(C + base + cb) = pk;
  }
}

// ---------------- mproj (MFMA) ----------------
__global__ __launch_bounds__(256) void k_mproj_mfma(
    const unsigned char* __restrict__ A, const bf16x8* __restrict__ Bpk,
    unsigned char* __restrict__ C)
{
  __shared__ float Ct[64][132];
  const int tid = threadIdx.x, l = tid & 63, w = tid >> 6;
  const int r0 = blockIdx.y * 64, n0 = blockIdx.x * 128;
  const int arow = r0 + w * 16 + (l & 15);
  const int kg0 = l >> 4;
  f32x4 acc[8] = {};
  for (int kc = 0; kc < 8; ++kc) {
    uint2 v = *(const uint2*)(A + (size_t)arow * 256 + kc * 32 + kg0 * 8);
    f32x2 p0 = cvt2_fp8(v.x), p1 = cvt2_fp8(v.x >> 16);
    f32x2 p2 = cvt2_fp8(v.y), p3 = cvt2_fp8(v.y >> 16);
    bf16x8 af;
    af[0] = (short)f32_bf16(p0.x); af[1] = (short)f32_bf16(p0.y);
    af[2] = (short)f32_bf16(p1.x); af[3] = (short)f32_bf16(p1.y);
    af[4] = (short)f32_bf16(p2.x); af[5] = (short)f32_bf16(p2.y);
    af[6] = (short)f32_bf16(p3.x); af[7] = (short)f32_bf16(p3.y);
    const bf16x8* bp = Bpk + (size_t)(kc * 4 + kg0) * 256 + n0 + (l & 15);
#pragma unroll
    for (int ct = 0; ct < 8; ++ct)
      acc[ct] = __builtin_amdgcn_mfma_f32_16x16x32_bf16(af, bp[ct * 16], acc[ct], 0, 0, 0);
  }
#pragma unroll
  for (int ct = 0; ct < 8; ++ct)
#pragma unroll
    for (int r = 0; r < 4; ++r)
      Ct[w * 16 + (l >> 4) * 4 + r][ct * 16 + (l & 15)] = acc[ct][r];
  __syncthreads();
  const int lr = tid >> 2, u0 = (tid & 3) * 8;
  size_t base = (size_t)(r0 + lr) * 256 + n0;
#pragma unroll
  for (int i = 0; i < 8; ++i) {
    int cb = (u0 + i) * 4;
    unsigned pk = f32_to_e4m3(Ct[lr][cb])        | (f32_to_e4m3(Ct[lr][cb + 1]) << 8)
                | (f32_to_e4m3(Ct[lr][cb + 2]) << 16) | (f32_to_e4m3(Ct[lr][cb + 3]) << 24);
    *(unsigned*)(C + base + cb) = pk;
  }
}

// ---------------- generic [1024x256] @ [256][1024] -> [1024][1024] f32 (prologue) ------
__global__ __launch_bounds__(256) void k_mv1024(
    const float* __restrict__ A, const float* __restrict__ WT, float* __restrict__ C)
{
  __shared__ float As[32][34];
  __shared__ float Bs[32][68];
  const int r0 = blockIdx.y * 32;
  const int n0 = blockIdx.x * 64;
  const int tid = threadIdx.x;
  const int tm = tid & 15, tn = tid >> 4;
  float acc[2][4] = {};
  for (int k0 = 0; k0 < 256; k0 += 32) {
    __syncthreads();
    {
      const int m = tid >> 3;
      const int kq = (tid & 7) * 4;
      const float* src = A + (size_t)(r0 + m) * 256 + k0 + kq;
      float4 v = *(const float4*)src;
      As[kq + 0][m] = v.x; As[kq + 1][m] = v.y; As[kq + 2][m] = v.z; As[kq + 3][m] = v.w;
    }
    {
      const int kb = tid >> 3;
      const int nq = (tid & 7) * 8;
      const float* src = WT + (size_t)(k0 + kb) * 1024 + n0 + nq;
      *(float4*)&Bs[kb][nq] = *(const float4*)src;
      *(float4*)&Bs[kb][nq + 4] = *(const float4*)(src + 4);
    }
    __syncthreads();
#pragma unroll
    for (int k = 0; k < 32; ++k) {
      float a0 = As[k][tm * 2 + 0], a1 = As[k][tm * 2 + 1];
      float4 bq = *(const float4*)&Bs[k][tn * 4];
      acc[0][0] += a0 * bq.x; acc[0][1] += a0 * bq.y; acc[0][2] += a0 * bq.z; acc[0][3] += a0 * bq.w;
      acc[1][0] += a1 * bq.x; acc[1][1] += a1 * bq.y; acc[1][2] += a1 * bq.z; acc[1][3] += a1 * bq.w;
    }
  }
#pragma unroll
  for (int i = 0; i < 2; ++i) {
    int r = r0 + tm * 2 + i;
    int j0 = n0 + tn * 4;
    float* dst = C + (size_t)r * 1024 + j0;
#pragma unroll
    for (int jj = 0; jj < 4; ++jj) dst[jj] = acc[i][jj];
  }
}

// ---------------- persistent decode loop: 1536 blocks, ONE barrier per step ----------
// blocks 0..1023 = attention (b = blk); 1024..1535 = whb(t+1) GEMM tiles.
// Barrier: leaf(blk&63, same-XCD groups, 128B-padded) -> mid(XCD) -> root -> gen.
__global__ __launch_bounds__(256, 6) void k_loop(
    const unsigned char* __restrict__ egs, const unsigned char* __restrict__ eps,
    const unsigned char* __restrict__ Mbuf, const unsigned char* __restrict__ embp,
    float* __restrict__ ws,
    const float* __restrict__ bq_g, const float* __restrict__ v_g,
    const float* __restrict__ v_p, const float* __restrict__ bq_p,
    float* __restrict__ out_logp, float* __restrict__ out_sels)
{
  __shared__ __align__(16) float smem[3264];
  __shared__ int act_s[NS];
  __shared__ int pos_s[NS];
  const int blk = blockIdx.x;
  const int tid = threadIdx.x;
  const float* BS = ws + OFF_BSUM;
  const float* WHHT = ws + OFF_WHHT;
  const unsigned* WQG2 = (const unsigned*)(ws + OFF_WQG2);
  float* h_glob = ws + OFF_H;
  unsigned* leaf = (unsigned*)(ws + OFF_BAR);          // 64 x 32 uints (128B apart)
  unsigned* mid  = leaf + 64 * 32;                     // 8 x 32 uints
  unsigned* root = mid + 8 * 32;
  unsigned* gen  = root + 1;

  if (blk < 1024 && tid < NS) { act_s[tid] = tid; pos_s[tid] = tid; }

  for (int t = 0; t < NS; ++t) {
    const int par = t & 1;
    const float* c_in    = ws + (par ? OFF_C1 : OFF_C0);
    float*       c_out   = ws + (par ? OFF_C0 : OFF_C1);
    const float* decp_in = ws + (par ? OFF_DECP1 : OFF_DECP0);
    float*       decp_out= ws + (par ? OFF_DECP0 : OFF_DECP1);
    const float* whb_in  = ws + (par ? OFF_WHB1 : OFF_WHB0);
    float*       whb_out = ws + (par ? OFF_WHB0 : OFF_WHB1);

    if (blk >= 1024) {
      // ======== mv: whb_out tile = h(t)[r0..r0+32) @ WHHT[:, n0..n0+64) ========
      float (*As)[34] = (float(*)[34])smem;
      float (*Bs)[68] = (float(*)[68])(smem + 1088);
      const int mid_id = blk - 1024;
      const int r0 = (mid_id >> 4) * 32;
      const int n0 = (mid_id & 15) * 64;
      const int tm = tid & 15, tn = tid >> 4;
      float acc[2][4] = {};
      for (int k0 = 0; k0 < 256; k0 += 32) {
        __syncthreads();
        {
          const int m = tid >> 3;
          const int kq = (tid & 7) * 4;
          const int r = r0 + m;
          float4 c4 = *(const float4*)(c_in + (size_t)r * 256 + k0 + kq);
          float cc[4] = {c4.x, c4.y, c4.z, c4.w};
#pragma unroll
          for (int j = 0; j < 4; ++j) {
            int hc = k0 + kq + j;
            float4 dp = *(const float4*)(decp_in + (size_t)r * 1024 + hc * 4);
            float4 wh = *(const float4*)(whb_in + (size_t)r * 1024 + hc * 4);
            float4 bs = *(const float4*)(BS + hc * 4);
            float gi = dp.x + wh.x + bs.x;
            float gf = dp.y + wh.y + bs.y;
            float gg = dp.z + wh.z + bs.z;
            float go = dp.w + wh.w + bs.w;
            float cn = fast_sigm(gf) * cc[j] + fast_sigm(gi) * fast_tanh(gg);
            As[kq + j][m] = fast_sigm(go) * fast_tanh(cn);
          }
        }
        {
          const int kb = tid >> 3;
          const int nq = (tid & 7) * 8;
          const float* src = WHHT + (size_t)(k0 + kb) * 1024 + n0 + nq;
          *(float4*)&Bs[kb][nq] = *(const float4*)src;
          *(float4*)&Bs[kb][nq + 4] = *(const float4*)(src + 4);
        }
        __syncthreads();
#pragma unroll
        for (int k = 0; k < 32; ++k) {
          float a0 = As[k][tm * 2 + 0], a1 = As[k][tm * 2 + 1];
          float4 bq = *(const float4*)&Bs[k][tn * 4];
          acc[0][0] += a0 * bq.x; acc[0][1] += a0 * bq.y; acc[0][2] += a0 * bq.z; acc[0][3] += a0 * bq.w;
          acc[1][0] += a1 * bq.x; acc[1][1] += a1 * bq.y; acc[1][2] += a1 * bq.z; acc[1][3] += a1 * bq.w;
        }
      }
#pragma unroll
      for (int i = 0; i < 2; ++i) {
        int r = r0 + tm * 2 + i;
        int j0 = n0 + tn * 4;
        float* dst = whb_out + (size_t)r * 1024 + j0;
#pragma unroll
        for (int jj = 0; jj < 4; ++jj) dst[jj] = acc[i][jj];
      }
    } else {
      // ================= attention (b = blk) =================
      float* hs    = smem;
      float* qpg_s = smem + 256;
      float* u_s   = smem + 512;
      float* wbuf  = smem + 768;
      float* qpp_s = smem + 1024;
      float* sred  = smem + 1480;
      float* svals = smem + 1488;
      int*   sidx  = (int*)(smem + 1496);
      int*   pick_p = (int*)(smem + 1504);
      const int b = blk;
      const int lane = tid & 63, wave = tid >> 6;
      const int nact = NS - t;

      // pre: LSTM cell for row b
      {
        float4 dp = *(const float4*)(decp_in + (size_t)b * 1024 + tid * 4);
        float4 wh = *(const float4*)(whb_in + (size_t)b * 1024 + tid * 4);
        float4 bs = *(const float4*)(BS + tid * 4);
        float gi = dp.x + wh.x + bs.x;
        float gf = dp.y + wh.y + bs.y;
        float gg = dp.z + wh.z + bs.z;
        float go = dp.w + wh.w + bs.w;
        float cprev = c_in[(size_t)b * 256 + tid];
        float cn = fast_sigm(gf) * cprev + fast_sigm(gi) * fast_tanh(gg);
        float hn = fast_sigm(go) * fast_tanh(cn);
        c_out[(size_t)b * 256 + tid] = cn;
        if (t == NS - 1) h_glob[(size_t)b * 256 + tid] = hn;
        hs[tid] = hn;
        u_s[tid] = NEG_INF;
      }
      __syncthreads();

      // P0: qp_g = h.WqTg (half2-packed) + bq_g
      {
        float a0 = 0.f, a1 = 0.f;
#pragma unroll 16
        for (int kk = 0; kk < 128; ++kk) {
          unsigned v = WQG2[kk * 256 + tid];
          __half2 hv = *reinterpret_cast<const __half2*>(&v);
          float2 f = __half22float2(hv);
          a0 = fmaf(hs[2 * kk], f.x, a0);
          a1 = fmaf(hs[2 * kk + 1], f.y, a1);
        }
        qpg_s[tid] = a0 + a1 + bq_g[tid];
      }
      __syncthreads();

      const unsigned char* egb = egs + (size_t)b * (NS * NH);
      const unsigned char* epb = eps + (size_t)b * (NS * NH);

      // P1: glimpse logits over ACTIVE rows (4 waves x 4-row ILP)
      {
        float4 qv; qv.x = qpg_s[lane*4]; qv.y = qpg_s[lane*4+1]; qv.z = qpg_s[lane*4+2]; qv.w = qpg_s[lane*4+3];
        float4 vv = *(const float4*)(v_g + lane * 4);
        int j = wave;
        for (; j + 12 < nact; j += 16) {
          int s0 = act_s[j], s1 = act_s[j + 4], s2 = act_s[j + 8], s3 = act_s[j + 12];
          unsigned r0 = *(const unsigned*)(egb + (size_t)s0 * NH + 4 * lane);
          unsigned r1 = *(const unsigned*)(egb + (size_t)s1 * NH + 4 * lane);
          unsigned r2 = *(const unsigned*)(egb + (size_t)s2 * NH + 4 * lane);
          unsigned r3 = *(const unsigned*)(egb + (size_t)s3 * NH + 4 * lane);
          f32x2 a01 = cvt2_fp8(r0), a23 = cvt2_fp8(r0 >> 16);
          f32x2 b01 = cvt2_fp8(r1), b23 = cvt2_fp8(r1 >> 16);
          f32x2 c01 = cvt2_fp8(r2), c23 = cvt2_fp8(r2 >> 16);
          f32x2 d01 = cvt2_fp8(r3), d23 = cvt2_fp8(r3 >> 16);
          float t0 = vv.x * fast_tanh(a01.x + qv.x);
          t0 = fmaf(vv.y, fast_tanh(a01.y + qv.y), t0);
          t0 = fmaf(vv.z, fast_tanh(a23.x + qv.z), t0);
          t0 = fmaf(vv.w, fast_tanh(a23.y + qv.w), t0);
          float t1 = vv.x * fast_tanh(b01.x + qv.x);
          t1 = fmaf(vv.y, fast_tanh(b01.y + qv.y), t1);
          t1 = fmaf(vv.z, fast_tanh(b23.x + qv.z), t1);
          t1 = fmaf(vv.w, fast_tanh(b23.y + qv.w), t1);
          float t2 = vv.x * fast_tanh(c01.x + qv.x);
          t2 = fmaf(vv.y, fast_tanh(c01.y + qv.y), t2);
          t2 = fmaf(vv.z, fast_tanh(c23.x + qv.z), t2);
          t2 = fmaf(vv.w, fast_tanh(c23.y + qv.w), t2);
          float t3 = vv.x * fast_tanh(d01.x + qv.x);
          t3 = fmaf(vv.y, fast_tanh(d01.y + qv.y), t3);
          t3 = fmaf(vv.z, fast_tanh(d23.x + qv.z), t3);
          t3 = fmaf(vv.w, fast_tanh(d23.y + qv.w), t3);
#pragma unroll
          for (int off = 32; off; off >>= 1) {
            t0 += __shfl_xor(t0, off); t1 += __shfl_xor(t1, off);
            t2 += __shfl_xor(t2, off); t3 += __shfl_xor(t3, off);
          }
          if (lane == 0) { u_s[s0] = t0; u_s[s1] = t1; u_s[s2] = t2; u_s[s3] = t3; }
        }
        for (; j < nact; j += 4) {
          int s0 = act_s[j];
          unsigned r0 = *(const unsigned*)(egb + (size_t)s0 * NH + 4 * lane);
          f32x2 a01 = cvt2_fp8(r0), a23 = cvt2_fp8(r0 >> 16);
          float t0 = vv.x * fast_tanh(a01.x + qv.x);
          t0 = fmaf(vv.y, fast_tanh(a01.y + qv.y), t0);
          t0 = fmaf(vv.z, fast_tanh(a23.x + qv.z), t0);
          t0 = fmaf(vv.w, fast_tanh(a23.y + qv.w), t0);
#pragma unroll
          for (int off = 32; off; off >>= 1) t0 += __shfl_xor(t0, off);
          if (lane == 0) u_s[s0] = t0;
        }
      }
      __syncthreads();

      // P2: softmax -> wbuf
      {
        float uv = (tid < NS) ? u_s[tid] : NEG_INF;
        float m = uv;
#pragma unroll
        for (int off = 32; off; off >>= 1) m = fmaxf(m, __shfl_xor(m, off));
        if (lane == 0) sred[wave] = m;
        __syncthreads();
        m = fmaxf(fmaxf(sred[0], sred[1]), fmaxf(sred[2], sred[3]));
        float ex = (uv == NEG_INF) ? 0.0f : fast_expn(uv - m);
        float sm = ex;
#pragma unroll
        for (int off = 32; off; off >>= 1) sm += __shfl_xor(sm, off);
        __syncthreads();
        if (lane == 0) sred[wave] = sm;
        __syncthreads();
        float Z = ((sred[0] + sred[1]) + sred[2]) + sred[3];
        wbuf[tid] = ex * fast_rcp(Z);
      }
      __syncthreads();

      // P3': qp_p = sum over ACTIVE s of w[s]*M[b][s][:] + bq_p (4-way ILP)
      {
        const unsigned char* Mb = Mbuf + (size_t)b * (NS * NH) + tid;
        float a0 = 0.f, a1 = 0.f, a2 = 0.f, a3 = 0.f;
        int j = 0;
        for (; j + 3 < nact; j += 4) {
          int s0 = act_s[j], s1 = act_s[j + 1], s2 = act_s[j + 2], s3 = act_s[j + 3];
          float m0 = cvt2_fp8((unsigned)Mb[(size_t)s0 * 256]).x;
          float m1 = cvt2_fp8((unsigned)Mb[(size_t)s1 * 256]).x;
          float m2 = cvt2_fp8((unsigned)Mb[(size_t)s2 * 256]).x;
          float m3 = cvt2_fp8((unsigned)Mb[(size_t)s3 * 256]).x;
          a0 = fmaf(wbuf[s0], m0, a0);
          a1 = fmaf(wbuf[s1], m1, a1);
          a2 = fmaf(wbuf[s2], m2, a2);
          a3 = fmaf(wbuf[s3], m3, a3);
        }
        for (; j < nact; ++j) {
          int s0 = act_s[j];
          a0 = fmaf(wbuf[s0], cvt2_fp8((unsigned)Mb[(size_t)s0 * 256]).x, a0);
        }
        qpp_s[tid] = ((a0 + a1) + (a2 + a3)) + bq_p[tid];
      }
      u_s[tid] = NEG_INF;
      __syncthreads();

      // P5: pointer logits over ACTIVE rows (4 waves x 4-row ILP)
      {
        float4 qv; qv.x = qpp_s[lane*4]; qv.y = qpp_s[lane*4+1]; qv.z = qpp_s[lane*4+2]; qv.w = qpp_s[lane*4+3];
        float4 vv = *(const float4*)(v_p + lane * 4);
        int j = wave;
        for (; j + 12 < nact; j += 16) {
          int s0 = act_s[j], s1 = act_s[j + 4], s2 = act_s[j + 8], s3 = act_s[j + 12];
          unsigned r0 = *(const unsigned*)(epb + (size_t)s0 * NH + 4 * lane);
          unsigned r1 = *(const unsigned*)(epb + (size_t)s1 * NH + 4 * lane);
          unsigned r2 = *(const unsigned*)(epb + (size_t)s2 * NH + 4 * lane);
          unsigned r3 = *(const unsigned*)(epb + (size_t)s3 * NH + 4 * lane);
          f32x2 a01 = cvt2_fp8(r0), a23 = cvt2_fp8(r0 >> 16);
          f32x2 b01 = cvt2_fp8(r1), b23 = cvt2_fp8(r1 >> 16);
          f32x2 c01 = cvt2_fp8(r2), c23 = cvt2_fp8(r2 >> 16);
          f32x2 d01 = cvt2_fp8(r3), d23 = cvt2_fp8(r3 >> 16);
          float t0 = vv.x * fast_tanh(a01.x + qv.x);
          t0 = fmaf(vv.y, fast_tanh(a01.y + qv.y), t0);
          t0 = fmaf(vv.z, fast_tanh(a23.x + qv.z), t0);
          t0 = fmaf(vv.w, fast_tanh(a23.y + qv.w), t0);
          float t1 = vv.x * fast_tanh(b01.x + qv.x);
          t1 = fmaf(vv.y, fast_tanh(b01.y + qv.y), t1);
          t1 = fmaf(vv.z, fast_tanh(b23.x + qv.z), t1);
          t1 = fmaf(vv.w, fast_tanh(b23.y + qv.w), t1);
          float t2 = vv.x * fast_tanh(c01.x + qv.x);
          t2 = fmaf(vv.y, fast_tanh(c01.y + qv.y), t2);
          t2 = fmaf(vv.z, fast_tanh(c23.x + qv.z), t2);
          t2 = fmaf(vv.w, fast_tanh(c23.y + qv.w), t2);
          float t3 = vv.x * fast_tanh(d01.x + qv.x);
          t3 = fmaf(vv.y, fast_tanh(d01.y + qv.y), t3);
          t3 = fmaf(vv.z, fast_tanh(d23.x + qv.z), t3);
          t3 = fmaf(vv.w, fast_tanh(d23.y + qv.w), t3);
#pragma unroll
          for (int off = 32; off; off >>= 1) {
            t0 += __shfl_xor(t0, off); t1 += __shfl_xor(t1, off);
            t2 += __shfl_xor(t2, off); t3 += __shfl_xor(t3, off);
          }
          if (lane == 0) {
            u_s[s0] = 10.0f * fast_tanh(t0); u_s[s1] = 10.0f * fast_tanh(t1);
            u_s[s2] = 10.0f * fast_tanh(t2); u_s[s3] = 10.0f * fast_tanh(t3);
          }
        }
        for (; j < nact; j += 4) {
          int s0 = act_s[j];
          unsigned r0 = *(const unsigned*)(epb + (size_t)s0 * NH + 4 * lane);
          f32x2 a01 = cvt2_fp8(r0), a23 = cvt2_fp8(r0 >> 16);
          float t0 = vv.x * fast_tanh(a01.x + qv.x);
          t0 = fmaf(vv.y, fast_tanh(a01.y + qv.y), t0);
          t0 = fmaf(vv.z, fast_tanh(a23.x + qv.z), t0);
          t0 = fmaf(vv.w, fast_tanh(a23.y + qv.w), t0);
#pragma unroll
          for (int off = 32; off; off >>= 1) t0 += __shfl_xor(t0, off);
          if (lane == 0) u_s[s0] = 10.0f * fast_tanh(t0);
        }
      }
      __syncthreads();

      // P6: log_softmax, store, argmax, LDS active-list update, gather embp
      {
        float uv = (tid < NS) ? u_s[tid] : NEG_INF;
        float m = uv;
#pragma unroll
        for (int off = 32; off; off >>= 1) m = fmaxf(m, __shfl_xor(m, off));
        if (lane == 0) sred[wave] = m;
        __syncthreads();
        m = fmaxf(fmaxf(sred[0], sred[1]), fmaxf(sred[2], sred[3]));
        float ex = (uv == NEG_INF) ? 0.0f : fast_expn(uv - m);
        float sm = ex;
#pragma unroll
        for (int off = 32; off; off >>= 1) sm += __shfl_xor(sm, off);
        __syncthreads();
        if (lane == 0) sred[wave] = sm;
        __syncthreads();
        float Z = ((sred[0] + sred[1]) + sred[2]) + sred[3];
        float lse = fast_log2(Z) * LN2;
        float lp = (uv - m) - lse;
        if (tid < NS) {
          float lp_store = fmaxf(lp, -3.0e38f);  // -inf -> huge finite (harness nan guard)
          __builtin_nontemporal_store(lp_store,
              &out_logp[(size_t)b * (NS * NS) + (size_t)t * NS + tid]);
        }
        float av = lp; int ai = tid;
#pragma unroll
        for (int off = 32; off; off >>= 1) {
          float ov = __shfl_xor(av, off);
          int oi = __shfl_xor(ai, off);
          if (ov > av || (ov == av && oi < ai)) { av = ov; ai = oi; }
        }
        if (lane == 0) { svals[wave] = av; sidx[wave] = ai; }
        __syncthreads();
        if (tid == 0) {
          float bv = svals[0]; int bi = sidx[0];
          for (int wv = 1; wv < 4; ++wv) {
            if (svals[wv] > bv || (svals[wv] == bv && sidx[wv] < bi)) { bv = svals[wv]; bi = sidx[wv]; }
          }
          *pick_p = bi;
          __builtin_nontemporal_store((float)bi, &out_sels[(size_t)b * NS + t]);
          int j = pos_s[bi];
          int last = act_s[nact - 1];
          act_s[j] = last;
          pos_s[last] = j;
        }
        __syncthreads();
        const int s = *pick_p;
        const unsigned char* er = embp + ((size_t)s * NB + b) * 1024;
        unsigned v = __builtin_nontemporal_load((const unsigned*)(er + tid * 4));
        f32x2 lo = cvt2_fp8(v), hi = cvt2_fp8(v >> 16);
        float4 o4; o4.x = lo.x; o4.y = lo.y; o4.z = hi.x; o4.w = hi.y;
        *(float4*)(decp_out + (size_t)b * 1024 + tid * 4) = o4;
      }
    }

    // ======== grid barrier (one per step) ========
    __syncthreads();
    if (tid == 0) {
      __threadfence();
      unsigned g = (unsigned)t;
      int l = blk & 63;
      if (atomicAdd(&leaf[l * 32], 1u) == g * 24u + 23u) {
        int mx = l & 7;
        if (atomicAdd(&mid[mx * 32], 1u) == g * 8u + 7u) {
          if (atomicAdd(root, 1u) == g * 8u + 7u) {
            __threadfence();
            atomicExch(gen, g + 1u);
          }
        }
      }
      unsigned spin = 0;
      while (__hip_atomic_load(gen, __ATOMIC_ACQUIRE, __HIP_MEMORY_SCOPE_AGENT) <= g) {
        __builtin_amdgcn_s_sleep(2);
        if (++spin > 400000000u) break;   // bounded bail: visible failure, never a hang
      }
      __threadfence();
    }
    __syncthreads();
  }
}

// ---------------- final h/c copy ----------------
__global__ __launch_bounds__(256) void k_out_hc(
    const float* __restrict__ h, const float* __restrict__ c, float* __restrict__ out)
{
  int i = blockIdx.x * 256 + threadIdx.x;
  if (i < NB * NH) {
    out[OUT_H + i] = h[i];
    out[OUT_C + i] = c[i];
  }
}

// ---------------- host ----------------
extern "C" void kernel_launch(void* const* d_in, const int* in_sizes, int n_in,
                              void* d_out, int out_size, void* d_ws, size_t ws_size,
                              hipStream_t stream)
{
  const float* dec0   = (const float*)d_in[0];
  const float* emb    = (const float*)d_in[1];
  const float* h0     = (const float*)d_in[2];
  const float* c0     = (const float*)d_in[3];
  const float* ctx    = (const float*)d_in[4];
  const float* W_ih   = (const float*)d_in[5];
  const float* W_hh   = (const float*)d_in[6];
  const float* b_ih   = (const float*)d_in[7];
  const float* b_hh   = (const float*)d_in[8];
  const float* Wq_g   = (const float*)d_in[9];
  const float* bq_g   = (const float*)d_in[10];
  const float* Wref_g = (const float*)d_in[11];
  const float* bref_g = (const float*)d_in[12];
  const float* v_g    = (const float*)d_in[13];
  const float* Wq_p   = (const float*)d_in[14];
  const float* bq_p   = (const float*)d_in[15];
  const float* Wref_p = (const float*)d_in[16];
  const float* bref_p = (const float*)d_in[17];
  const float* v_p    = (const float*)d_in[18];

  float* ws = (float*)d_ws;
  float* out = (float*)d_out;
  unsigned char* egs  = (unsigned char*)(ws + OFF_EGS);
  unsigned char* eps  = (unsigned char*)(ws + OFF_EPS);
  unsigned char* embp = (unsigned char*)(ws + OFF_EMBP);
  unsigned char* Mbuf = (unsigned char*)(ws + OFF_M);

  k_init<<<dim3(1024), dim3(256), 0, stream>>>(h0, c0, W_ih, W_hh, b_ih, b_hh,
                                               Wq_g, Wq_p, Wref_g, Wref_p, ws);
  k_eproj_mfma<<<dim3(2, 3200), dim3(256), 0, stream>>>(
      ctx, (const bf16x8*)(ws + OFF_BPK_RG), bref_g, egs);
  k_eproj_mfma<<<dim3(2, 3200), dim3(256), 0, stream>>>(
      ctx, (const bf16x8*)(ws + OFF_BPK_RP), bref_p, eps);
  k_embproj_mfma<<<dim3(8, 3200), dim3(256), 0, stream>>>(
      emb, (const bf16x8*)(ws + OFF_BPK_IH), embp);
  k_mproj_mfma<<<dim3(2, 3200), dim3(256), 0, stream>>>(
      egs, (const bf16x8*)(ws + OFF_BPK_QP), Mbuf);
  k_mv1024<<<dim3(16, 32), dim3(256), 0, stream>>>(dec0, ws + OFF_WIHT, ws + OFF_DECP0);
  k_mv1024<<<dim3(16, 32), dim3(256), 0, stream>>>(ws + OFF_H, ws + OFF_WHHT, ws + OFF_WHB0);

  k_loop<<<dim3(1536), dim3(256), 0, stream>>>(
      egs, eps, Mbuf, embp, ws, bq_g, v_g, v_p, bq_p, out, out + OUT_SELS);

  // t=199 (odd): final c in OFF_C0; h in OFF_H
  k_out_hc<<<dim3(1024), dim3(256), 0, stream>>>(ws + OFF_H, ws + OFF_C0, out);
}

// Round 16
// 11103.777 us; speedup vs baseline: 14.9152x; 14.9152x over previous
//
#include <hip/hip_runtime.h>
#include <hip/hip_fp16.h>

// Problem sizes
static constexpr int NB = 1024;   // batch
static constexpr int NS = 200;    // seq len
static constexpr int NH = 256;    // hidden == embed
static constexpr int NG4 = 1024;  // 4*H

#define NEG_INF (-__builtin_inff())
static constexpr float LOG2E = 1.4426950408889634f;
static constexpr float LN2   = 0.6931471805599453f;

// ---------------- workspace layout (float offsets) ----------------
static constexpr size_t OFF_EGS   = 0;                                    // fp8 [B][200][256]
static constexpr size_t OFF_EPS   = OFF_EGS  + (size_t)NB*NS*NH/4;        // fp8 [B][200][256]
static constexpr size_t OFF_EMBP  = OFF_EPS  + (size_t)NB*NS*NH/4;        // fp8 [S][B][1024] emb@WihT
static constexpr size_t OFF_M     = OFF_EMBP + (size_t)NS*NB*NG4/4;       // fp8 [B][200][256] eg@WqpT
static constexpr size_t OFF_WIHT  = OFF_M    + (size_t)NB*NS*NH/4;        // f32 [256][1024] gate-interleaved
static constexpr size_t OFF_WHHT  = OFF_WIHT + (size_t)NH*NG4;            // f32 [256][1024]
static constexpr size_t OFF_BSUM  = OFF_WHHT + (size_t)NH*NG4;            // f32 [1024]
static constexpr size_t OFF_WQG2  = OFF_BSUM + 1024;                      // half2-packed WqTg [128][256]
static constexpr size_t OFF_H     = OFF_WQG2 + (size_t)128*256;           // f32 [B][256]
static constexpr size_t OFF_C0    = OFF_H    + (size_t)NB*NH;             // c parity (f32)
static constexpr size_t OFF_C1    = OFF_C0   + (size_t)NB*NH;
static constexpr size_t OFF_DECP0 = OFF_C1   + (size_t)NB*NH;             // decp parity: fp8 [B][1024]
static constexpr size_t OFF_DECP1 = OFF_DECP0 + (size_t)NB*NG4/4;
static constexpr size_t OFF_WHB0  = OFF_DECP1 + (size_t)NB*NG4/4;         // whb parity: bf16 [B][1024]
static constexpr size_t OFF_WHB1  = OFF_WHB0 + (size_t)NB*NG4/2;
// bf16x8-packed B fragments
static constexpr size_t OFF_BPK_IH = OFF_WHB1 + (size_t)NB*NG4/2;         // [32][1024] x 16B
static constexpr size_t OFF_BPK_RG = OFF_BPK_IH + (size_t)32*1024*4;      // [32][256] x 16B
static constexpr size_t OFF_BPK_RP = OFF_BPK_RG + (size_t)32*256*4;
static constexpr size_t OFF_BPK_QP = OFF_BPK_RP + (size_t)32*256*4;

// ---------------- output layout (float offsets) ----------------
static constexpr size_t OUT_SELS = (size_t)NB*NS*NS;   // log_p first
static constexpr size_t OUT_H    = OUT_SELS + (size_t)NB*NS;
static constexpr size_t OUT_C    = OUT_H + (size_t)NB*NH;

// ---------------- types / fast math ----------------
typedef float f32x2 __attribute__((ext_vector_type(2)));
typedef float f32x4 __attribute__((ext_vector_type(4)));
typedef short bf16x8 __attribute__((ext_vector_type(8)));   // 8 bf16 in 4 VGPRs

__device__ __forceinline__ float fast_exp2(float x) {
  float d; asm("v_exp_f32 %0, %1" : "=v"(d) : "v"(x)); return d;
}
__device__ __forceinline__ float fast_rcp(float x) {
  float d; asm("v_rcp_f32 %0, %1" : "=v"(d) : "v"(x)); return d;
}
__device__ __forceinline__ float fast_log2(float x) {
  float d; asm("v_log_f32 %0, %1" : "=v"(d) : "v"(x)); return d;
}
__device__ __forceinline__ float fast_tanh(float x) {
  float e = fast_exp2(x * (2.0f * LOG2E));
  return fmaf(-2.0f, fast_rcp(e + 1.0f), 1.0f);
}
__device__ __forceinline__ float fast_sigm(float x) {
  float e = fast_exp2(x * (-LOG2E));
  return fast_rcp(1.0f + e);
}
__device__ __forceinline__ float fast_expn(float a) {   // exp(a), a<=0 (or -inf -> 0)
  return fast_exp2(a * LOG2E);
}
__device__ __forceinline__ f32x2 cvt2_fp8(unsigned int u) {
  f32x2 d; asm("v_cvt_pk_f32_fp8 %0, %1" : "=v"(d) : "v"(u)); return d;
}
__device__ __forceinline__ unsigned int f32_to_e4m3(float x) {
  x = fminf(fmaxf(x, -448.0f), 448.0f);
  unsigned int u = __float_as_uint(x);
  unsigned int s = (u >> 24) & 0x80u;
  unsigned int au = u & 0x7fffffffu;
  if (au < 0x3c800000u) return s;
  unsigned int r = au + 0x7ffffu + ((au >> 20) & 1u);
  unsigned int expf8 = (r >> 23) - 120u;
  unsigned int man = (r >> 20) & 7u;
  return s | (expf8 << 3) | man;
}
// f32 -> bf16 (RNE)
__device__ __forceinline__ unsigned f32_bf16(float x) {
  unsigned u = __float_as_uint(x);
  unsigned r = u + 0x7fffu + ((u >> 16) & 1u);
  return r >> 16;
}
__device__ __forceinline__ float bf16_f32(unsigned u) {   // u = low 16 bits
  return __uint_as_float(u << 16);
}

// ---------------- init: weight transforms + bf16 fragment packing ----------------
__global__ __launch_bounds__(256) void k_init(
    const float* __restrict__ h0, const float* __restrict__ c0,
    const float* __restrict__ W_ih, const float* __restrict__ W_hh,
    const float* __restrict__ b_ih, const float* __restrict__ b_hh,
    const float* __restrict__ Wq_g, const float* __restrict__ Wq_p,
    const float* __restrict__ Wref_g, const float* __restrict__ Wref_p,
    float* __restrict__ ws)
{
  const int i0 = blockIdx.x * 256 + threadIdx.x;
  const int stride = gridDim.x * 256;
  float* WIHT = ws + OFF_WIHT;
  float* WHHT = ws + OFF_WHHT;
  float* BS   = ws + OFF_BSUM;
  unsigned* WQG2 = (unsigned*)(ws + OFF_WQG2);
  // gate-interleaved col j = h*4+g  -> source row = g*256+h
  for (int t = i0; t < NH * NG4; t += stride) {
    int k = t >> 10, j = t & 1023;
    int row = (j & 3) * 256 + (j >> 2);
    WIHT[t] = W_ih[row * NH + k];
    WHHT[t] = W_hh[row * NH + k];
  }
  for (int t = i0; t < 1024; t += stride) {
    int row = (t & 3) * 256 + (t >> 2);
    BS[t] = b_ih[row] + b_hh[row];
  }
  for (int t = i0; t < 128 * 256; t += stride) {
    int kk = t >> 8, o = t & 255;
    __half lo = __float2half(Wq_g[o * NH + 2 * kk]);
    __half hi = __float2half(Wq_g[o * NH + 2 * kk + 1]);
    unsigned v = ((unsigned)__half_as_ushort(hi) << 16) | (unsigned)__half_as_ushort(lo);
    WQG2[t] = v;
  }
  // bf16x8 fragment packs: Bpk[(kg)*N + n] = { bf16(B[kg*8+j][n]) }
  {
    uint4* BP = (uint4*)(ws + OFF_BPK_IH);
    for (int t = i0; t < 32 * 1024; t += stride) {
      int kg = t >> 10, n = t & 1023;
      int row = (n & 3) * 256 + (n >> 2);
      unsigned us[8];
#pragma unroll
      for (int j = 0; j < 8; ++j) us[j] = f32_bf16(W_ih[row * NH + kg * 8 + j]) & 0xffffu;
      BP[t] = (uint4){ us[0]|(us[1]<<16), us[2]|(us[3]<<16), us[4]|(us[5]<<16), us[6]|(us[7]<<16) };
    }
  }
  {
    uint4* BG = (uint4*)(ws + OFF_BPK_RG);
    uint4* BR = (uint4*)(ws + OFF_BPK_RP);
    uint4* BQ = (uint4*)(ws + OFF_BPK_QP);
    for (int t = i0; t < 32 * 256; t += stride) {
      int kg = t >> 8, n = t & 255;
      unsigned g[8], r[8], q[8];
#pragma unroll
      for (int j = 0; j < 8; ++j) {
        int k = kg * 8 + j;
        g[j] = f32_bf16(Wref_g[n * NH + k]) & 0xffffu;
        r[j] = f32_bf16(Wref_p[n * NH + k]) & 0xffffu;
        q[j] = f32_bf16(Wq_p[n * NH + k]) & 0xffffu;
      }
      BG[t] = (uint4){ g[0]|(g[1]<<16), g[2]|(g[3]<<16), g[4]|(g[5]<<16), g[6]|(g[7]<<16) };
      BR[t] = (uint4){ r[0]|(r[1]<<16), r[2]|(r[3]<<16), r[4]|(r[5]<<16), r[6]|(r[7]<<16) };
      BQ[t] = (uint4){ q[0]|(q[1]<<16), q[2]|(q[3]<<16), q[4]|(q[5]<<16), q[6]|(q[7]<<16) };
    }
  }
  float* hbuf = ws + OFF_H;
  float* cbuf = ws + OFF_C0;
  for (int t = i0; t < NB * NH; t += stride) {
    hbuf[t] = h0[t]; cbuf[t] = c0[t];
  }
}

// ---------------- MFMA proj kernels: 64 rows x ALL cols per block (A staged once) ------
// A staged as bf16 in LDS; wave w owns rows [w*16, +16); loop over 16-col tiles.
// C/D frag layout: col = lane&15, row = (lane>>4)*4 + r. Epilogue bounces through
// per-wave LDS (in-wave ds ordering; no cross-wave sharing -> no barrier needed).

// embproj: A f32 [204800][256], B N=1024, out fp8 row-major [R][1024]
__global__ __launch_bounds__(256) void k_embproj2(
    const float* __restrict__ A, const bf16x8* __restrict__ Bpk,
    unsigned char* __restrict__ C)
{
  __shared__ unsigned short As16[64][264];
  __shared__ float CtW[4][16][20];
  const int tid = threadIdx.x, l = tid & 63, w = tid >> 6;
  const int r0 = blockIdx.x * 64;
  // stage A (f32 -> bf16 LDS)
#pragma unroll
  for (int q = 0; q < 16; ++q) {
    int idx = q * 256 + tid;
    int row = idx >> 6, c4 = (idx & 63) * 4;
    float4 v = *(const float4*)(A + (size_t)(r0 + row) * 256 + c4);
    *(unsigned*)&As16[row][c4]     = f32_bf16(v.x) | (f32_bf16(v.y) << 16);
    *(unsigned*)&As16[row][c4 + 2] = f32_bf16(v.z) | (f32_bf16(v.w) << 16);
  }
  __syncthreads();
  const int arow = w * 16 + (l & 15);
  const int kg0 = l >> 4;
  bf16x8 afr[8];
#pragma unroll
  for (int kc = 0; kc < 8; ++kc)
    afr[kc] = *(const bf16x8*)&As16[arow][kc * 32 + kg0 * 8];
  for (int ct = 0; ct < 64; ++ct) {
    f32x4 acc = {};
    const bf16x8* bp = Bpk + ct * 16 + (l & 15);
#pragma unroll
    for (int kc = 0; kc < 8; ++kc)
      acc = __builtin_amdgcn_mfma_f32_16x16x32_bf16(afr[kc], bp[(size_t)(kc * 4 + kg0) * 1024], acc, 0, 0, 0);
#pragma unroll
    for (int r = 0; r < 4; ++r) CtW[w][(l >> 4) * 4 + r][l & 15] = acc[r];
    float4 cv = *(const float4*)&CtW[w][l >> 2][(l & 3) * 4];
    unsigned pk = f32_to_e4m3(cv.x) | (f32_to_e4m3(cv.y) << 8)
                | (f32_to_e4m3(cv.z) << 16) | (f32_to_e4m3(cv.w) << 24);
    *(unsigned*)(C + (size_t)(r0 + w * 16 + (l >> 2)) * 1024 + ct * 16 + (l & 3) * 4) = pk;
  }
}

// eproj: A f32 ctx [204800][256] (row R = s*B + b), B N=256 + bias, out fp8 [b][s][256]
__global__ __launch_bounds__(256) void k_eproj2(
    const float* __restrict__ A, const bf16x8* __restrict__ Bpk,
    const float* __restrict__ bias, unsigned char* __restrict__ C)
{
  __shared__ unsigned short As16[64][264];
  __shared__ float CtW[4][16][20];
  __shared__ float bias_s[256];
  const int tid = threadIdx.x, l = tid & 63, w = tid >> 6;
  const int r0 = blockIdx.x * 64;
  bias_s[tid] = bias[tid];
#pragma unroll
  for (int q = 0; q < 16; ++q) {
    int idx = q * 256 + tid;
    int row = idx >> 6, c4 = (idx & 63) * 4;
    float4 v = *(const float4*)(A + (size_t)(r0 + row) * 256 + c4);
    *(unsigned*)&As16[row][c4]     = f32_bf16(v.x) | (f32_bf16(v.y) << 16);
    *(unsigned*)&As16[row][c4 + 2] = f32_bf16(v.z) | (f32_bf16(v.w) << 16);
  }
  __syncthreads();
  const int arow = w * 16 + (l & 15);
  const int kg0 = l >> 4;
  bf16x8 afr[8];
#pragma unroll
  for (int kc = 0; kc < 8; ++kc)
    afr[kc] = *(const bf16x8*)&As16[arow][kc * 32 + kg0 * 8];
  const int R = r0 + w * 16 + (l >> 2);
  const int b = R & 1023, s = R >> 10;
  for (int ct = 0; ct < 16; ++ct) {
    f32x4 acc = {};
    const bf16x8* bp = Bpk + ct * 16 + (l & 15);
#pragma unroll
    for (int kc = 0; kc < 8; ++kc)
      acc = __builtin_amdgcn_mfma_f32_16x16x32_bf16(afr[kc], bp[(size_t)(kc * 4 + kg0) * 256], acc, 0, 0, 0);
#pragma unroll
    for (int r = 0; r < 4; ++r) CtW[w][(l >> 4) * 4 + r][l & 15] = acc[r];
    float4 cv = *(const float4*)&CtW[w][l >> 2][(l & 3) * 4];
    int cb = ct * 16 + (l & 3) * 4;
    unsigned pk = f32_to_e4m3(cv.x + bias_s[cb])       | (f32_to_e4m3(cv.y + bias_s[cb + 1]) << 8)
                | (f32_to_e4m3(cv.z + bias_s[cb + 2]) << 16) | (f32_to_e4m3(cv.w + bias_s[cb + 3]) << 24);
    *(unsigned*)(C + (size_t)b * (NS * NH) + (size_t)s * NH + cb) = pk;
  }
}

// mproj: A fp8 [204800][256], B N=256, out fp8 row-major [R][256]
__global__ __launch_bounds__(256) void k_mproj2(
    const unsigned char* __restrict__ A, const bf16x8* __restrict__ Bpk,
    unsigned char* __restrict__ C)
{
  __shared__ unsigned short As16[64][264];
  __shared__ float CtW[4][16][20];
  const int tid = threadIdx.x, l = tid & 63, w = tid >> 6;
  const int r0 = blockIdx.x * 64;
#pragma unroll
  for (int q = 0; q < 16; ++q) {
    int idx = q * 256 + tid;          // 4096 u32 total
    int row = idx >> 6, c4 = (idx & 63) * 4;
    unsigned v = *(const unsigned*)(A + (size_t)(r0 + row) * 256 + c4);
    f32x2 lo = cvt2_fp8(v), hi = cvt2_fp8(v >> 16);
    *(unsigned*)&As16[row][c4]     = f32_bf16(lo.x) | (f32_bf16(lo.y) << 16);
    *(unsigned*)&As16[row][c4 + 2] = f32_bf16(hi.x) | (f32_bf16(hi.y) << 16);
  }
  __syncthreads();
  const int arow = w * 16 + (l & 15);
  const int kg0 = l >> 4;
  bf16x8 afr[8];
#pragma unroll
  for (int kc = 0; kc < 8; ++kc)
    afr[kc] = *(const bf16x8*)&As16[arow][kc * 32 + kg0 * 8];
  for (int ct = 0; ct < 16; ++ct) {
    f32x4 acc = {};
    const bf16x8* bp = Bpk + ct * 16 + (l & 15);
#pragma unroll
    for (int kc = 0; kc < 8; ++kc)
      acc = __builtin_amdgcn_mfma_f32_16x16x32_bf16(afr[kc], bp[(size_t)(kc * 4 + kg0) * 256], acc, 0, 0, 0);
#pragma unroll
    for (int r = 0; r < 4; ++r) CtW[w][(l >> 4) * 4 + r][l & 15] = acc[r];
    float4 cv = *(const float4*)&CtW[w][l >> 2][(l & 3) * 4];
    unsigned pk = f32_to_e4m3(cv.x) | (f32_to_e4m3(cv.y) << 8)
                | (f32_to_e4m3(cv.z) << 16) | (f32_to_e4m3(cv.w) << 24);
    *(unsigned*)(C + (size_t)(r0 + w * 16 + (l >> 2)) * 256 + ct * 16 + (l & 3) * 4) = pk;
  }
}

// ---------------- [1024x256] @ [256][1024] GEMM; MODE 1: fp8 out, MODE 2: bf16 out ----
template <int MODE>
__global__ __launch_bounds__(256) void k_mv1024t(
    const float* __restrict__ A, const float* __restrict__ WT, void* __restrict__ Cv)
{
  __shared__ float As[32][34];
  __shared__ float Bs[32][68];
  const int r0 = blockIdx.y * 32;
  const int n0 = blockIdx.x * 64;
  const int tid = threadIdx.x;
  const int tm = tid & 15, tn = tid >> 4;
  float acc[2][4] = {};
  for (int k0 = 0; k0 < 256; k0 += 32) {
    __syncthreads();
    {
      const int m = tid >> 3;
      const int kq = (tid & 7) * 4;
      const float* src = A + (size_t)(r0 + m) * 256 + k0 + kq;
      float4 v = *(const float4*)src;
      As[kq + 0][m] = v.x; As[kq + 1][m] = v.y; As[kq + 2][m] = v.z; As[kq + 3][m] = v.w;
    }
    {
      const int kb = tid >> 3;
      const int nq = (tid & 7) * 8;
      const float* src = WT + (size_t)(k0 + kb) * 1024 + n0 + nq;
      *(float4*)&Bs[kb][nq] = *(const float4*)src;
      *(float4*)&Bs[kb][nq + 4] = *(const float4*)(src + 4);
    }
    __syncthreads();
#pragma unroll
    for (int k = 0; k < 32; ++k) {
      float a0 = As[k][tm * 2 + 0], a1 = As[k][tm * 2 + 1];
      float4 bq = *(const float4*)&Bs[k][tn * 4];
      acc[0][0] += a0 * bq.x; acc[0][1] += a0 * bq.y; acc[0][2] += a0 * bq.z; acc[0][3] += a0 * bq.w;
      acc[1][0] += a1 * bq.x; acc[1][1] += a1 * bq.y; acc[1][2] += a1 * bq.z; acc[1][3] += a1 * bq.w;
    }
  }
#pragma unroll
  for (int i = 0; i < 2; ++i) {
    int r = r0 + tm * 2 + i;
    int j0 = n0 + tn * 4;
    if (MODE == 1) {
      unsigned pk = f32_to_e4m3(acc[i][0]) | (f32_to_e4m3(acc[i][1]) << 8)
                  | (f32_to_e4m3(acc[i][2]) << 16) | (f32_to_e4m3(acc[i][3]) << 24);
      ((unsigned*)Cv)[(size_t)r * 256 + (j0 >> 2)] = pk;
    } else {
      uint2 pk;
      pk.x = f32_bf16(acc[i][0]) | (f32_bf16(acc[i][1]) << 16);
      pk.y = f32_bf16(acc[i][2]) | (f32_bf16(acc[i][3]) << 16);
      *(uint2*)((unsigned short*)Cv + (size_t)r * 1024 + j0) = pk;
    }
  }
}

// ---------------- k_step: ONE dispatch per decode step ----------------
// blocks 0..1023 : attention (b = blk); 1024..1535: whb(t+1) GEMM tiles (h recomputed)
__global__ __launch_bounds__(256) void k_step(
    const unsigned char* __restrict__ egs, const unsigned char* __restrict__ eps,
    const unsigned char* __restrict__ Mbuf, const unsigned char* __restrict__ embp,
    float* __restrict__ ws,
    const float* __restrict__ bq_g, const float* __restrict__ v_g,
    const float* __restrict__ v_p, const float* __restrict__ bq_p,
    float* __restrict__ out_logp, float* __restrict__ out_sels,
    const float* __restrict__ c_in, float* __restrict__ c_out,
    const unsigned char* __restrict__ decp_in, unsigned char* __restrict__ decp_out,
    const unsigned short* __restrict__ whb_in, unsigned short* __restrict__ whb_out,
    int* __restrict__ act_g, int* __restrict__ pos_g,
    const int t)
{
  __shared__ __align__(16) float smem[3264];
  const int blk = blockIdx.x;
  const int tid = threadIdx.x;
  const float* BS = ws + OFF_BSUM;

  if (blk >= 1024) {
    // ======== mv: whb_out tile = h(t)[r0..r0+32) @ WHHT[:, n0..n0+64) ========
    float (*As)[34] = (float(*)[34])smem;
    float (*Bs)[68] = (float(*)[68])(smem + 1088);
    const float* WHHT = ws + OFF_WHHT;
    const int mid = blk - 1024;
    const int r0 = (mid >> 4) * 32;
    const int n0 = (mid & 15) * 64;
    const int tm = tid & 15, tn = tid >> 4;
    float acc[2][4] = {};
    for (int k0 = 0; k0 < 256; k0 += 32) {
      __syncthreads();
      {
        const int m = tid >> 3;
        const int kq = (tid & 7) * 4;
        const int r = r0 + m;
        float4 c4 = *(const float4*)(c_in + (size_t)r * 256 + k0 + kq);
        float cc[4] = {c4.x, c4.y, c4.z, c4.w};
#pragma unroll
        for (int j = 0; j < 4; ++j) {
          int hc = k0 + kq + j;
          unsigned dpu = *(const unsigned*)(decp_in + (size_t)r * 1024 + hc * 4);
          f32x2 d01 = cvt2_fp8(dpu), d23 = cvt2_fp8(dpu >> 16);
          uint2 whu = *(const uint2*)(whb_in + (size_t)r * 1024 + hc * 4);
          float4 bs = *(const float4*)(BS + hc * 4);
          float gi = d01.x + bf16_f32(whu.x & 0xffffu) + bs.x;
          float gf = d01.y + bf16_f32(whu.x >> 16) + bs.y;
          float gg = d23.x + bf16_f32(whu.y & 0xffffu) + bs.z;
          float go = d23.y + bf16_f32(whu.y >> 16) + bs.w;
          float cn = fast_sigm(gf) * cc[j] + fast_sigm(gi) * fast_tanh(gg);
          As[kq + j][m] = fast_sigm(go) * fast_tanh(cn);
        }
      }
      {
        const int kb = tid >> 3;
        const int nq = (tid & 7) * 8;
        const float* src = WHHT + (size_t)(k0 + kb) * 1024 + n0 + nq;
        *(float4*)&Bs[kb][nq] = *(const float4*)src;
        *(float4*)&Bs[kb][nq + 4] = *(const float4*)(src + 4);
      }
      __syncthreads();
#pragma unroll
      for (int k = 0; k < 32; ++k) {
        float a0 = As[k][tm * 2 + 0], a1 = As[k][tm * 2 + 1];
        float4 bq = *(const float4*)&Bs[k][tn * 4];
        acc[0][0] += a0 * bq.x; acc[0][1] += a0 * bq.y; acc[0][2] += a0 * bq.z; acc[0][3] += a0 * bq.w;
        acc[1][0] += a1 * bq.x; acc[1][1] += a1 * bq.y; acc[1][2] += a1 * bq.z; acc[1][3] += a1 * bq.w;
      }
    }
#pragma unroll
    for (int i = 0; i < 2; ++i) {
      int r = r0 + tm * 2 + i;
      int j0 = n0 + tn * 4;
      uint2 pk;
      pk.x = f32_bf16(acc[i][0]) | (f32_bf16(acc[i][1]) << 16);
      pk.y = f32_bf16(acc[i][2]) | (f32_bf16(acc[i][3]) << 16);
      *(uint2*)(whb_out + (size_t)r * 1024 + j0) = pk;
    }
    return;
  }

  // ================= attention part =================
  float* hs    = smem;
  float* qpg_s = smem + 256;
  float* u_s   = smem + 512;
  float* wbuf  = smem + 768;
  float* qpp_s = smem + 1024;
  int*   act_s = (int*)(smem + 1280);   // 200
  float* sred  = smem + 1480;
  float* svals = smem + 1488;
  int*   sidx  = (int*)(smem + 1496);
  int*   pick_p = (int*)(smem + 1504);

  const int b = blk;
  const int lane = tid & 63, wave = tid >> 6;
  const int nact = NS - t;
  float* h_glob = ws + OFF_H;
  const unsigned* WQG2 = (const unsigned*)(ws + OFF_WQG2);

  // pre: LSTM cell for row b
  {
    unsigned dpu = *(const unsigned*)(decp_in + (size_t)b * 1024 + tid * 4);
    f32x2 d01 = cvt2_fp8(dpu), d23 = cvt2_fp8(dpu >> 16);
    uint2 whu = *(const uint2*)(whb_in + (size_t)b * 1024 + tid * 4);
    float4 bs = *(const float4*)(BS + tid * 4);
    float gi = d01.x + bf16_f32(whu.x & 0xffffu) + bs.x;
    float gf = d01.y + bf16_f32(whu.x >> 16) + bs.y;
    float gg = d23.x + bf16_f32(whu.y & 0xffffu) + bs.z;
    float go = d23.y + bf16_f32(whu.y >> 16) + bs.w;
    float cprev = c_in[(size_t)b * 256 + tid];
    float cn = fast_sigm(gf) * cprev + fast_sigm(gi) * fast_tanh(gg);
    float hn = fast_sigm(go) * fast_tanh(cn);
    c_out[(size_t)b * 256 + tid] = cn;
    if (t == NS - 1) h_glob[(size_t)b * 256 + tid] = hn;
    hs[tid] = hn;
    u_s[tid] = NEG_INF;
  }
  if (tid < NS) act_s[tid] = act_g[(size_t)b * NS + tid];
  __syncthreads();

  // P0: qp_g = h.WqTg (half2-packed) + bq_g
  {
    float a0 = 0.f, a1 = 0.f;
#pragma unroll 16
    for (int kk = 0; kk < 128; ++kk) {
      unsigned v = WQG2[kk * 256 + tid];
      __half2 hv = *reinterpret_cast<const __half2*>(&v);
      float2 f = __half22float2(hv);
      a0 = fmaf(hs[2 * kk], f.x, a0);
      a1 = fmaf(hs[2 * kk + 1], f.y, a1);
    }
    qpg_s[tid] = a0 + a1 + bq_g[tid];
  }
  __syncthreads();

  const unsigned char* egb = egs + (size_t)b * (NS * NH);
  const unsigned char* epb = eps + (size_t)b * (NS * NH);

  // P1: glimpse logits over ACTIVE rows (4 waves x 4-row ILP)
  {
    float4 qv; qv.x = qpg_s[lane*4]; qv.y = qpg_s[lane*4+1]; qv.z = qpg_s[lane*4+2]; qv.w = qpg_s[lane*4+3];
    float4 vv = *(const float4*)(v_g + lane * 4);
    int j = wave;
    for (; j + 12 < nact; j += 16) {
      int s0 = act_s[j], s1 = act_s[j + 4], s2 = act_s[j + 8], s3 = act_s[j + 12];
      unsigned r0 = *(const unsigned*)(egb + (size_t)s0 * NH + 4 * lane);
      unsigned r1 = *(const unsigned*)(egb + (size_t)s1 * NH + 4 * lane);
      unsigned r2 = *(const unsigned*)(egb + (size_t)s2 * NH + 4 * lane);
      unsigned r3 = *(const unsigned*)(egb + (size_t)s3 * NH + 4 * lane);
      f32x2 a01 = cvt2_fp8(r0), a23 = cvt2_fp8(r0 >> 16);
      f32x2 b01 = cvt2_fp8(r1), b23 = cvt2_fp8(r1 >> 16);
      f32x2 c01 = cvt2_fp8(r2), c23 = cvt2_fp8(r2 >> 16);
      f32x2 d01 = cvt2_fp8(r3), d23 = cvt2_fp8(r3 >> 16);
      float t0 = vv.x * fast_tanh(a01.x + qv.x);
      t0 = fmaf(vv.y, fast_tanh(a01.y + qv.y), t0);
      t0 = fmaf(vv.z, fast_tanh(a23.x + qv.z), t0);
      t0 = fmaf(vv.w, fast_tanh(a23.y + qv.w), t0);
      float t1 = vv.x * fast_tanh(b01.x + qv.x);
      t1 = fmaf(vv.y, fast_tanh(b01.y + qv.y), t1);
      t1 = fmaf(vv.z, fast_tanh(b23.x + qv.z), t1);
      t1 = fmaf(vv.w, fast_tanh(b23.y + qv.w), t1);
      float t2 = vv.x * fast_tanh(c01.x + qv.x);
      t2 = fmaf(vv.y, fast_tanh(c01.y + qv.y), t2);
      t2 = fmaf(vv.z, fast_tanh(c23.x + qv.z), t2);
      t2 = fmaf(vv.w, fast_tanh(c23.y + qv.w), t2);
      float t3 = vv.x * fast_tanh(d01.x + qv.x);
      t3 = fmaf(vv.y, fast_tanh(d01.y + qv.y), t3);
      t3 = fmaf(vv.z, fast_tanh(d23.x + qv.z), t3);
      t3 = fmaf(vv.w, fast_tanh(d23.y + qv.w), t3);
#pragma unroll
      for (int off = 32; off; off >>= 1) {
        t0 += __shfl_xor(t0, off); t1 += __shfl_xor(t1, off);
        t2 += __shfl_xor(t2, off); t3 += __shfl_xor(t3, off);
      }
      if (lane == 0) { u_s[s0] = t0; u_s[s1] = t1; u_s[s2] = t2; u_s[s3] = t3; }
    }
    for (; j < nact; j += 4) {
      int s0 = act_s[j];
      unsigned r0 = *(const unsigned*)(egb + (size_t)s0 * NH + 4 * lane);
      f32x2 a01 = cvt2_fp8(r0), a23 = cvt2_fp8(r0 >> 16);
      float t0 = vv.x * fast_tanh(a01.x + qv.x);
      t0 = fmaf(vv.y, fast_tanh(a01.y + qv.y), t0);
      t0 = fmaf(vv.z, fast_tanh(a23.x + qv.z), t0);
      t0 = fmaf(vv.w, fast_tanh(a23.y + qv.w), t0);
#pragma unroll
      for (int off = 32; off; off >>= 1) t0 += __shfl_xor(t0, off);
      if (lane == 0) u_s[s0] = t0;
    }
  }
  __syncthreads();

  // P2: softmax -> wbuf
  {
    float uv = (tid < NS) ? u_s[tid] : NEG_INF;
    float m = uv;
#pragma unroll
    for (int off = 32; off; off >>= 1) m = fmaxf(m, __shfl_xor(m, off));
    if (lane == 0) sred[wave] = m;
    __syncthreads();
    m = fmaxf(fmaxf(sred[0], sred[1]), fmaxf(sred[2], sred[3]));
    float ex = (uv == NEG_INF) ? 0.0f : fast_expn(uv - m);
    float sm = ex;
#pragma unroll
    for (int off = 32; off; off >>= 1) sm += __shfl_xor(sm, off);
    __syncthreads();
    if (lane == 0) sred[wave] = sm;
    __syncthreads();
    float Z = ((sred[0] + sred[1]) + sred[2]) + sred[3];
    wbuf[tid] = ex * fast_rcp(Z);
  }
  __syncthreads();

  // P3': qp_p = sum over ACTIVE s of w[s]*M[b][s][:] + bq_p (4-way ILP)
  {
    const unsigned char* Mb = Mbuf + (size_t)b * (NS * NH) + tid;
    float a0 = 0.f, a1 = 0.f, a2 = 0.f, a3 = 0.f;
    int j = 0;
    for (; j + 3 < nact; j += 4) {
      int s0 = act_s[j], s1 = act_s[j + 1], s2 = act_s[j + 2], s3 = act_s[j + 3];
      float m0 = cvt2_fp8((unsigned)Mb[(size_t)s0 * 256]).x;
      float m1 = cvt2_fp8((unsigned)Mb[(size_t)s1 * 256]).x;
      float m2 = cvt2_fp8((unsigned)Mb[(size_t)s2 * 256]).x;
      float m3 = cvt2_fp8((unsigned)Mb[(size_t)s3 * 256]).x;
      a0 = fmaf(wbuf[s0], m0, a0);
      a1 = fmaf(wbuf[s1], m1, a1);
      a2 = fmaf(wbuf[s2], m2, a2);
      a3 = fmaf(wbuf[s3], m3, a3);
    }
    for (; j < nact; ++j) {
      int s0 = act_s[j];
      a0 = fmaf(wbuf[s0], cvt2_fp8((unsigned)Mb[(size_t)s0 * 256]).x, a0);
    }
    qpp_s[tid] = ((a0 + a1) + (a2 + a3)) + bq_p[tid];
  }
  u_s[tid] = NEG_INF;
  __syncthreads();

  // P5: pointer logits over ACTIVE rows (4 waves x 4-row ILP)
  {
    float4 qv; qv.x = qpp_s[lane*4]; qv.y = qpp_s[lane*4+1]; qv.z = qpp_s[lane*4+2]; qv.w = qpp_s[lane*4+3];
    float4 vv = *(const float4*)(v_p + lane * 4);
    int j = wave;
    for (; j + 12 < nact; j += 16) {
      int s0 = act_s[j], s1 = act_s[j + 4], s2 = act_s[j + 8], s3 = act_s[j + 12];
      unsigned r0 = *(const unsigned*)(epb + (size_t)s0 * NH + 4 * lane);
      unsigned r1 = *(const unsigned*)(epb + (size_t)s1 * NH + 4 * lane);
      unsigned r2 = *(const unsigned*)(epb + (size_t)s2 * NH + 4 * lane);
      unsigned r3 = *(const unsigned*)(epb + (size_t)s3 * NH + 4 * lane);
      f32x2 a01 = cvt2_fp8(r0), a23 = cvt2_fp8(r0 >> 16);
      f32x2 b01 = cvt2_fp8(r1), b23 = cvt2_fp8(r1 >> 16);
      f32x2 c01 = cvt2_fp8(r2), c23 = cvt2_fp8(r2 >> 16);
      f32x2 d01 = cvt2_fp8(r3), d23 = cvt2_fp8(r3 >> 16);
      float t0 = vv.x * fast_tanh(a01.x + qv.x);
      t0 = fmaf(vv.y, fast_tanh(a01.y + qv.y), t0);
      t0 = fmaf(vv.z, fast_tanh(a23.x + qv.z), t0);
      t0 = fmaf(vv.w, fast_tanh(a23.y + qv.w), t0);
      float t1 = vv.x * fast_tanh(b01.x + qv.x);
      t1 = fmaf(vv.y, fast_tanh(b01.y + qv.y), t1);
      t1 = fmaf(vv.z, fast_tanh(b23.x + qv.z), t1);
      t1 = fmaf(vv.w, fast_tanh(b23.y + qv.w), t1);
      float t2 = vv.x * fast_tanh(c01.x + qv.x);
      t2 = fmaf(vv.y, fast_tanh(c01.y + qv.y), t2);
      t2 = fmaf(vv.z, fast_tanh(c23.x + qv.z), t2);
      t2 = fmaf(vv.w, fast_tanh(c23.y + qv.w), t2);
      float t3 = vv.x * fast_tanh(d01.x + qv.x);
      t3 = fmaf(vv.y, fast_tanh(d01.y + qv.y), t3);
      t3 = fmaf(vv.z, fast_tanh(d23.x + qv.z), t3);
      t3 = fmaf(vv.w, fast_tanh(d23.y + qv.w), t3);
#pragma unroll
      for (int off = 32; off; off >>= 1) {
        t0 += __shfl_xor(t0, off); t1 += __shfl_xor(t1, off);
        t2 += __shfl_xor(t2, off); t3 += __shfl_xor(t3, off);
      }
      if (lane == 0) {
        u_s[s0] = 10.0f * fast_tanh(t0); u_s[s1] = 10.0f * fast_tanh(t1);
        u_s[s2] = 10.0f * fast_tanh(t2); u_s[s3] = 10.0f * fast_tanh(t3);
      }
    }
    for (; j < nact; j += 4) {
      int s0 = act_s[j];
      unsigned r0 = *(const unsigned*)(epb + (size_t)s0 * NH + 4 * lane);
      f32x2 a01 = cvt2_fp8(r0), a23 = cvt2_fp8(r0 >> 16);
      float t0 = vv.x * fast_tanh(a01.x + qv.x);
      t0 = fmaf(vv.y, fast_tanh(a01.y + qv.y), t0);
      t0 = fmaf(vv.z, fast_tanh(a23.x + qv.z), t0);
      t0 = fmaf(vv.w, fast_tanh(a23.y + qv.w), t0);
#pragma unroll
      for (int off = 32; off; off >>= 1) t0 += __shfl_xor(t0, off);
      if (lane == 0) u_s[s0] = 10.0f * fast_tanh(t0);
    }
  }
  __syncthreads();

  // P6: log_softmax, store, argmax, active-list update, gather embp -> decp_out (fp8 raw)
  {
    float uv = (tid < NS) ? u_s[tid] : NEG_INF;
    float m = uv;
#pragma unroll
    for (int off = 32; off; off >>= 1) m = fmaxf(m, __shfl_xor(m, off));
    if (lane == 0) sred[wave] = m;
    __syncthreads();
    m = fmaxf(fmaxf(sred[0], sred[1]), fmaxf(sred[2], sred[3]));
    float ex = (uv == NEG_INF) ? 0.0f : fast_expn(uv - m);
    float sm = ex;
#pragma unroll
    for (int off = 32; off; off >>= 1) sm += __shfl_xor(sm, off);
    __syncthreads();
    if (lane == 0) sred[wave] = sm;
    __syncthreads();
    float Z = ((sred[0] + sred[1]) + sred[2]) + sred[3];
    float lse = fast_log2(Z) * LN2;
    float lp = (uv - m) - lse;
    if (tid < NS) {
      float lp_store = fmaxf(lp, -3.0e38f);  // -inf -> huge finite (harness nan guard)
      __builtin_nontemporal_store(lp_store,
          &out_logp[(size_t)b * (NS * NS) + (size_t)t * NS + tid]);
    }
    float av = lp; int ai = tid;
#pragma unroll
    for (int off = 32; off; off >>= 1) {
      float ov = __shfl_xor(av, off);
      int oi = __shfl_xor(ai, off);
      if (ov > av || (ov == av && oi < ai)) { av = ov; ai = oi; }
    }
    if (lane == 0) { svals[wave] = av; sidx[wave] = ai; }
    __syncthreads();
    if (tid == 0) {
      float bv = svals[0]; int bi = sidx[0];
      for (int wv = 1; wv < 4; ++wv) {
        if (svals[wv] > bv || (svals[wv] == bv && sidx[wv] < bi)) { bv = svals[wv]; bi = sidx[wv]; }
      }
      *pick_p = bi;
      __builtin_nontemporal_store((float)bi, &out_sels[(size_t)b * NS + t]);
      int j = pos_g[(size_t)b * NS + bi];
      int last = act_g[(size_t)b * NS + (nact - 1)];
      act_g[(size_t)b * NS + j] = last;
      pos_g[(size_t)b * NS + last] = j;
    }
    __syncthreads();
    const int s = *pick_p;
    const unsigned char* er = embp + ((size_t)s * NB + b) * 1024;
    unsigned v = __builtin_nontemporal_load((const unsigned*)(er + tid * 4));
    *(unsigned*)(decp_out + (size_t)b * 1024 + tid * 4) = v;   // raw fp8 (lossless)
  }
}

// ---------------- act/pos init (global, per replay) ----------------
__global__ __launch_bounds__(256) void k_actinit(int* __restrict__ act, int* __restrict__ pos)
{
  int i = blockIdx.x * 256 + threadIdx.x;
  if (i < NB * NS) {
    int s = i % NS;
    act[i] = s; pos[i] = s;
  }
}

// ---------------- final h/c copy ----------------
__global__ __launch_bounds__(256) void k_out_hc(
    const float* __restrict__ h, const float* __restrict__ c, float* __restrict__ out)
{
  int i = blockIdx.x * 256 + threadIdx.x;
  if (i < NB * NH) {
    out[OUT_H + i] = h[i];
    out[OUT_C + i] = c[i];
  }
}

// ---------------- host ----------------
extern "C" void kernel_launch(void* const* d_in, const int* in_sizes, int n_in,
                              void* d_out, int out_size, void* d_ws, size_t ws_size,
                              hipStream_t stream)
{
  const float* dec0   = (const float*)d_in[0];
  const float* emb    = (const float*)d_in[1];
  const float* h0     = (const float*)d_in[2];
  const float* c0     = (const float*)d_in[3];
  const float* ctx    = (const float*)d_in[4];
  const float* W_ih   = (const float*)d_in[5];
  const float* W_hh   = (const float*)d_in[6];
  const float* b_ih   = (const float*)d_in[7];
  const float* b_hh   = (const float*)d_in[8];
  const float* Wq_g   = (const float*)d_in[9];
  const float* bq_g   = (const float*)d_in[10];
  const float* Wref_g = (const float*)d_in[11];
  const float* bref_g = (const float*)d_in[12];
  const float* v_g    = (const float*)d_in[13];
  const float* Wq_p   = (const float*)d_in[14];
  const float* bq_p   = (const float*)d_in[15];
  const float* Wref_p = (const float*)d_in[16];
  const float* bref_p = (const float*)d_in[17];
  const float* v_p    = (const float*)d_in[18];

  float* ws = (float*)d_ws;
  float* out = (float*)d_out;
  unsigned char* egs  = (unsigned char*)(ws + OFF_EGS);
  unsigned char* eps  = (unsigned char*)(ws + OFF_EPS);
  unsigned char* embp = (unsigned char*)(ws + OFF_EMBP);
  unsigned char* Mbuf = (unsigned char*)(ws + OFF_M);
  // act/pos live after the Bpk region
  static constexpr size_t OFF_ACT = OFF_BPK_QP + (size_t)32*256*4;
  static constexpr size_t OFF_POS = OFF_ACT + (size_t)NB*NS;
  int* act = (int*)(ws + OFF_ACT);
  int* pos = (int*)(ws + OFF_POS);

  k_init<<<dim3(1024), dim3(256), 0, stream>>>(h0, c0, W_ih, W_hh, b_ih, b_hh,
                                               Wq_g, Wq_p, Wref_g, Wref_p, ws);
  k_actinit<<<dim3((NB * NS + 255) / 256), dim3(256), 0, stream>>>(act, pos);
  k_eproj2<<<dim3(3200), dim3(256), 0, stream>>>(
      ctx, (const bf16x8*)(ws + OFF_BPK_RG), bref_g, egs);
  k_eproj2<<<dim3(3200), dim3(256), 0, stream>>>(
      ctx, (const bf16x8*)(ws + OFF_BPK_RP), bref_p, eps);
  k_embproj2<<<dim3(3200), dim3(256), 0, stream>>>(
      emb, (const bf16x8*)(ws + OFF_BPK_IH), embp);
  k_mproj2<<<dim3(3200), dim3(256), 0, stream>>>(
      egs, (const bf16x8*)(ws + OFF_BPK_QP), Mbuf);
  k_mv1024t<1><<<dim3(16, 32), dim3(256), 0, stream>>>(
      dec0, ws + OFF_WIHT, (void*)(ws + OFF_DECP0));
  k_mv1024t<2><<<dim3(16, 32), dim3(256), 0, stream>>>(
      ws + OFF_H, ws + OFF_WHHT, (void*)(ws + OFF_WHB0));

  for (int t = 0; t < NS; ++t) {
    const int par = t & 1;
    const float* c_in    = ws + (par ? OFF_C1 : OFF_C0);
    float*       c_outp  = ws + (par ? OFF_C0 : OFF_C1);
    const unsigned char* decp_in = (const unsigned char*)(ws + (par ? OFF_DECP1 : OFF_DECP0));
    unsigned char*       decp_o  = (unsigned char*)(ws + (par ? OFF_DECP0 : OFF_DECP1));
    const unsigned short* whb_in = (const unsigned short*)(ws + (par ? OFF_WHB1 : OFF_WHB0));
    unsigned short*       whb_o  = (unsigned short*)(ws + (par ? OFF_WHB0 : OFF_WHB1));
    k_step<<<dim3(1536), dim3(256), 0, stream>>>(
        egs, eps, Mbuf, embp, ws, bq_g, v_g, v_p, bq_p,
        out, out + OUT_SELS,
        c_in, c_outp, decp_in, decp_o, whb_in, whb_o, act, pos, t);
  }
  // t=199 (odd): final c in OFF_C0; h in OFF_H
  k_out_hc<<<dim3(1024), dim3(256), 0, stream>>>(ws + OFF_H, ws + OFF_C0, out);
}

// Round 17
// 10865.000 us; speedup vs baseline: 15.2430x; 1.0220x over previous
//
#include <hip/hip_runtime.h>
#include <hip/hip_fp16.h>

// Problem sizes
static constexpr int NB = 1024;   // batch
static constexpr int NS = 200;    // seq len
static constexpr int NH = 256;    // hidden == embed
static constexpr int NG4 = 1024;  // 4*H

#define NEG_INF (-__builtin_inff())
static constexpr float LOG2E = 1.4426950408889634f;
static constexpr float LN2   = 0.6931471805599453f;

// ---------------- workspace layout (float offsets) ----------------
static constexpr size_t OFF_EGS   = 0;                                    // fp8 [B][200][256]
static constexpr size_t OFF_EPS   = OFF_EGS  + (size_t)NB*NS*NH/4;        // fp8 [B][200][256]
static constexpr size_t OFF_EMBP  = OFF_EPS  + (size_t)NB*NS*NH/4;        // fp8 [S][B][1024] emb@WihT
static constexpr size_t OFF_M     = OFF_EMBP + (size_t)NS*NB*NG4/4;       // fp8 [B][200][256] eg@WqpT
static constexpr size_t OFF_WIHT  = OFF_M    + (size_t)NB*NS*NH/4;        // f32 [256][1024] gate-interleaved
static constexpr size_t OFF_WHHT  = OFF_WIHT + (size_t)NH*NG4;            // f32 [256][1024]
static constexpr size_t OFF_BSUM  = OFF_WHHT + (size_t)NH*NG4;            // f32 [1024]
static constexpr size_t OFF_WQG2  = OFF_BSUM + 1024;                      // half2-packed WqTg [128][256]
static constexpr size_t OFF_H     = OFF_WQG2 + (size_t)128*256;           // f32 [B][256]
static constexpr size_t OFF_C0    = OFF_H    + (size_t)NB*NH;             // c parity (f32)
static constexpr size_t OFF_C1    = OFF_C0   + (size_t)NB*NH;
static constexpr size_t OFF_DECP0 = OFF_C1   + (size_t)NB*NH;             // decp parity: fp8 [B][1024]
static constexpr size_t OFF_DECP1 = OFF_DECP0 + (size_t)NB*NG4/4;
static constexpr size_t OFF_WHB0  = OFF_DECP1 + (size_t)NB*NG4/4;         // whb parity: bf16 [B][1024]
static constexpr size_t OFF_WHB1  = OFF_WHB0 + (size_t)NB*NG4/2;
// bf16x8-packed B fragments
static constexpr size_t OFF_BPK_IH = OFF_WHB1 + (size_t)NB*NG4/2;         // [32][1024] x 16B
static constexpr size_t OFF_BPK_RG = OFF_BPK_IH + (size_t)32*1024*4;      // [32][256] x 16B
static constexpr size_t OFF_BPK_RP = OFF_BPK_RG + (size_t)32*256*4;
static constexpr size_t OFF_BPK_QP = OFF_BPK_RP + (size_t)32*256*4;

// ---------------- output layout (float offsets) ----------------
static constexpr size_t OUT_SELS = (size_t)NB*NS*NS;   // log_p first
static constexpr size_t OUT_H    = OUT_SELS + (size_t)NB*NS;
static constexpr size_t OUT_C    = OUT_H + (size_t)NB*NH;

// ---------------- types / fast math ----------------
typedef float f32x2 __attribute__((ext_vector_type(2)));
typedef float f32x4 __attribute__((ext_vector_type(4)));
typedef short bf16x8 __attribute__((ext_vector_type(8)));   // 8 bf16 in 4 VGPRs

__device__ __forceinline__ float fast_exp2(float x) {
  float d; asm("v_exp_f32 %0, %1" : "=v"(d) : "v"(x)); return d;
}
__device__ __forceinline__ float fast_rcp(float x) {
  float d; asm("v_rcp_f32 %0, %1" : "=v"(d) : "v"(x)); return d;
}
__device__ __forceinline__ float fast_log2(float x) {
  float d; asm("v_log_f32 %0, %1" : "=v"(d) : "v"(x)); return d;
}
__device__ __forceinline__ float fast_tanh(float x) {
  float e = fast_exp2(x * (2.0f * LOG2E));
  return fmaf(-2.0f, fast_rcp(e + 1.0f), 1.0f);
}
__device__ __forceinline__ float fast_sigm(float x) {
  float e = fast_exp2(x * (-LOG2E));
  return fast_rcp(1.0f + e);
}
__device__ __forceinline__ float fast_expn(float a) {   // exp(a), a<=0 (or -inf -> 0)
  return fast_exp2(a * LOG2E);
}
__device__ __forceinline__ f32x2 cvt2_fp8(unsigned int u) {
  f32x2 d; asm("v_cvt_pk_f32_fp8 %0, %1" : "=v"(d) : "v"(u)); return d;
}
__device__ __forceinline__ unsigned int f32_to_e4m3(float x) {
  x = fminf(fmaxf(x, -448.0f), 448.0f);
  unsigned int u = __float_as_uint(x);
  unsigned int s = (u >> 24) & 0x80u;
  unsigned int au = u & 0x7fffffffu;
  if (au < 0x3c800000u) return s;
  unsigned int r = au + 0x7ffffu + ((au >> 20) & 1u);
  unsigned int expf8 = (r >> 23) - 120u;
  unsigned int man = (r >> 20) & 7u;
  return s | (expf8 << 3) | man;
}
// f32 -> bf16 (RNE)
__device__ __forceinline__ unsigned f32_bf16(float x) {
  unsigned u = __float_as_uint(x);
  unsigned r = u + 0x7fffu + ((u >> 16) & 1u);
  return r >> 16;
}
__device__ __forceinline__ float bf16_f32(unsigned u) {   // u = low 16 bits
  return __uint_as_float(u << 16);
}

// logits helper: one e-row dot (4 tanh terms) given packed fp8 row word
__device__ __forceinline__ float row_dot(unsigned r, float4 qv, float4 vv) {
  f32x2 lo = cvt2_fp8(r), hi = cvt2_fp8(r >> 16);
  float t = vv.x * fast_tanh(lo.x + qv.x);
  t = fmaf(vv.y, fast_tanh(lo.y + qv.y), t);
  t = fmaf(vv.z, fast_tanh(hi.x + qv.z), t);
  t = fmaf(vv.w, fast_tanh(hi.y + qv.w), t);
  return t;
}

// ---------------- init: weight transforms + bf16 fragment packing ----------------
__global__ __launch_bounds__(256) void k_init(
    const float* __restrict__ h0, const float* __restrict__ c0,
    const float* __restrict__ W_ih, const float* __restrict__ W_hh,
    const float* __restrict__ b_ih, const float* __restrict__ b_hh,
    const float* __restrict__ Wq_g, const float* __restrict__ Wq_p,
    const float* __restrict__ Wref_g, const float* __restrict__ Wref_p,
    float* __restrict__ ws)
{
  const int i0 = blockIdx.x * 256 + threadIdx.x;
  const int stride = gridDim.x * 256;
  float* WIHT = ws + OFF_WIHT;
  float* WHHT = ws + OFF_WHHT;
  float* BS   = ws + OFF_BSUM;
  unsigned* WQG2 = (unsigned*)(ws + OFF_WQG2);
  for (int t = i0; t < NH * NG4; t += stride) {
    int k = t >> 10, j = t & 1023;
    int row = (j & 3) * 256 + (j >> 2);
    WIHT[t] = W_ih[row * NH + k];
    WHHT[t] = W_hh[row * NH + k];
  }
  for (int t = i0; t < 1024; t += stride) {
    int row = (t & 3) * 256 + (t >> 2);
    BS[t] = b_ih[row] + b_hh[row];
  }
  for (int t = i0; t < 128 * 256; t += stride) {
    int kk = t >> 8, o = t & 255;
    __half lo = __float2half(Wq_g[o * NH + 2 * kk]);
    __half hi = __float2half(Wq_g[o * NH + 2 * kk + 1]);
    unsigned v = ((unsigned)__half_as_ushort(hi) << 16) | (unsigned)__half_as_ushort(lo);
    WQG2[t] = v;
  }
  {
    uint4* BP = (uint4*)(ws + OFF_BPK_IH);
    for (int t = i0; t < 32 * 1024; t += stride) {
      int kg = t >> 10, n = t & 1023;
      int row = (n & 3) * 256 + (n >> 2);
      unsigned us[8];
#pragma unroll
      for (int j = 0; j < 8; ++j) us[j] = f32_bf16(W_ih[row * NH + kg * 8 + j]) & 0xffffu;
      BP[t] = (uint4){ us[0]|(us[1]<<16), us[2]|(us[3]<<16), us[4]|(us[5]<<16), us[6]|(us[7]<<16) };
    }
  }
  {
    uint4* BG = (uint4*)(ws + OFF_BPK_RG);
    uint4* BR = (uint4*)(ws + OFF_BPK_RP);
    uint4* BQ = (uint4*)(ws + OFF_BPK_QP);
    for (int t = i0; t < 32 * 256; t += stride) {
      int kg = t >> 8, n = t & 255;
      unsigned g[8], r[8], q[8];
#pragma unroll
      for (int j = 0; j < 8; ++j) {
        int k = kg * 8 + j;
        g[j] = f32_bf16(Wref_g[n * NH + k]) & 0xffffu;
        r[j] = f32_bf16(Wref_p[n * NH + k]) & 0xffffu;
        q[j] = f32_bf16(Wq_p[n * NH + k]) & 0xffffu;
      }
      BG[t] = (uint4){ g[0]|(g[1]<<16), g[2]|(g[3]<<16), g[4]|(g[5]<<16), g[6]|(g[7]<<16) };
      BR[t] = (uint4){ r[0]|(r[1]<<16), r[2]|(r[3]<<16), r[4]|(r[5]<<16), r[6]|(r[7]<<16) };
      BQ[t] = (uint4){ q[0]|(q[1]<<16), q[2]|(q[3]<<16), q[4]|(q[5]<<16), q[6]|(q[7]<<16) };
    }
  }
  float* hbuf = ws + OFF_H;
  float* cbuf = ws + OFF_C0;
  for (int t = i0; t < NB * NH; t += stride) {
    hbuf[t] = h0[t]; cbuf[t] = c0[t];
  }
}

// ---------------- MFMA proj kernels: 64 rows x ALL cols per block ----------------
__global__ __launch_bounds__(256) void k_embproj2(
    const float* __restrict__ A, const bf16x8* __restrict__ Bpk,
    unsigned char* __restrict__ C)
{
  __shared__ unsigned short As16[64][264];
  __shared__ float CtW[4][16][20];
  const int tid = threadIdx.x, l = tid & 63, w = tid >> 6;
  const int r0 = blockIdx.x * 64;
#pragma unroll
  for (int q = 0; q < 16; ++q) {
    int idx = q * 256 + tid;
    int row = idx >> 6, c4 = (idx & 63) * 4;
    float4 v = *(const float4*)(A + (size_t)(r0 + row) * 256 + c4);
    *(unsigned*)&As16[row][c4]     = f32_bf16(v.x) | (f32_bf16(v.y) << 16);
    *(unsigned*)&As16[row][c4 + 2] = f32_bf16(v.z) | (f32_bf16(v.w) << 16);
  }
  __syncthreads();
  const int arow = w * 16 + (l & 15);
  const int kg0 = l >> 4;
  bf16x8 afr[8];
#pragma unroll
  for (int kc = 0; kc < 8; ++kc)
    afr[kc] = *(const bf16x8*)&As16[arow][kc * 32 + kg0 * 8];
  for (int ct = 0; ct < 64; ++ct) {
    f32x4 acc = {};
    const bf16x8* bp = Bpk + ct * 16 + (l & 15);
#pragma unroll
    for (int kc = 0; kc < 8; ++kc)
      acc = __builtin_amdgcn_mfma_f32_16x16x32_bf16(afr[kc], bp[(size_t)(kc * 4 + kg0) * 1024], acc, 0, 0, 0);
#pragma unroll
    for (int r = 0; r < 4; ++r) CtW[w][(l >> 4) * 4 + r][l & 15] = acc[r];
    float4 cv = *(const float4*)&CtW[w][l >> 2][(l & 3) * 4];
    unsigned pk = f32_to_e4m3(cv.x) | (f32_to_e4m3(cv.y) << 8)
                | (f32_to_e4m3(cv.z) << 16) | (f32_to_e4m3(cv.w) << 24);
    *(unsigned*)(C + (size_t)(r0 + w * 16 + (l >> 2)) * 1024 + ct * 16 + (l & 3) * 4) = pk;
  }
}

__global__ __launch_bounds__(256) void k_eproj2(
    const float* __restrict__ A, const bf16x8* __restrict__ Bpk,
    const float* __restrict__ bias, unsigned char* __restrict__ C)
{
  __shared__ unsigned short As16[64][264];
  __shared__ float CtW[4][16][20];
  __shared__ float bias_s[256];
  const int tid = threadIdx.x, l = tid & 63, w = tid >> 6;
  const int r0 = blockIdx.x * 64;
  bias_s[tid] = bias[tid];
#pragma unroll
  for (int q = 0; q < 16; ++q) {
    int idx = q * 256 + tid;
    int row = idx >> 6, c4 = (idx & 63) * 4;
    float4 v = *(const float4*)(A + (size_t)(r0 + row) * 256 + c4);
    *(unsigned*)&As16[row][c4]     = f32_bf16(v.x) | (f32_bf16(v.y) << 16);
    *(unsigned*)&As16[row][c4 + 2] = f32_bf16(v.z) | (f32_bf16(v.w) << 16);
  }
  __syncthreads();
  const int arow = w * 16 + (l & 15);
  const int kg0 = l >> 4;
  bf16x8 afr[8];
#pragma unroll
  for (int kc = 0; kc < 8; ++kc)
    afr[kc] = *(const bf16x8*)&As16[arow][kc * 32 + kg0 * 8];
  const int R = r0 + w * 16 + (l >> 2);
  const int b = R & 1023, s = R >> 10;
  for (int ct = 0; ct < 16; ++ct) {
    f32x4 acc = {};
    const bf16x8* bp = Bpk + ct * 16 + (l & 15);
#pragma unroll
    for (int kc = 0; kc < 8; ++kc)
      acc = __builtin_amdgcn_mfma_f32_16x16x32_bf16(afr[kc], bp[(size_t)(kc * 4 + kg0) * 256], acc, 0, 0, 0);
#pragma unroll
    for (int r = 0; r < 4; ++r) CtW[w][(l >> 4) * 4 + r][l & 15] = acc[r];
    float4 cv = *(const float4*)&CtW[w][l >> 2][(l & 3) * 4];
    int cb = ct * 16 + (l & 3) * 4;
    unsigned pk = f32_to_e4m3(cv.x + bias_s[cb])       | (f32_to_e4m3(cv.y + bias_s[cb + 1]) << 8)
                | (f32_to_e4m3(cv.z + bias_s[cb + 2]) << 16) | (f32_to_e4m3(cv.w + bias_s[cb + 3]) << 24);
    *(unsigned*)(C + (size_t)b * (NS * NH) + (size_t)s * NH + cb) = pk;
  }
}

__global__ __launch_bounds__(256) void k_mproj2(
    const unsigned char* __restrict__ A, const bf16x8* __restrict__ Bpk,
    unsigned char* __restrict__ C)
{
  __shared__ unsigned short As16[64][264];
  __shared__ float CtW[4][16][20];
  const int tid = threadIdx.x, l = tid & 63, w = tid >> 6;
  const int r0 = blockIdx.x * 64;
#pragma unroll
  for (int q = 0; q < 16; ++q) {
    int idx = q * 256 + tid;
    int row = idx >> 6, c4 = (idx & 63) * 4;
    unsigned v = *(const unsigned*)(A + (size_t)(r0 + row) * 256 + c4);
    f32x2 lo = cvt2_fp8(v), hi = cvt2_fp8(v >> 16);
    *(unsigned*)&As16[row][c4]     = f32_bf16(lo.x) | (f32_bf16(lo.y) << 16);
    *(unsigned*)&As16[row][c4 + 2] = f32_bf16(hi.x) | (f32_bf16(hi.y) << 16);
  }
  __syncthreads();
  const int arow = w * 16 + (l & 15);
  const int kg0 = l >> 4;
  bf16x8 afr[8];
#pragma unroll
  for (int kc = 0; kc < 8; ++kc)
    afr[kc] = *(const bf16x8*)&As16[arow][kc * 32 + kg0 * 8];
  for (int ct = 0; ct < 16; ++ct) {
    f32x4 acc = {};
    const bf16x8* bp = Bpk + ct * 16 + (l & 15);
#pragma unroll
    for (int kc = 0; kc < 8; ++kc)
      acc = __builtin_amdgcn_mfma_f32_16x16x32_bf16(afr[kc], bp[(size_t)(kc * 4 + kg0) * 256], acc, 0, 0, 0);
#pragma unroll
    for (int r = 0; r < 4; ++r) CtW[w][(l >> 4) * 4 + r][l & 15] = acc[r];
    float4 cv = *(const float4*)&CtW[w][l >> 2][(l & 3) * 4];
    unsigned pk = f32_to_e4m3(cv.x) | (f32_to_e4m3(cv.y) << 8)
                | (f32_to_e4m3(cv.z) << 16) | (f32_to_e4m3(cv.w) << 24);
    *(unsigned*)(C + (size_t)(r0 + w * 16 + (l >> 2)) * 256 + ct * 16 + (l & 3) * 4) = pk;
  }
}

// ---------------- [1024x256] @ [256][1024] GEMM; MODE 1: fp8 out, MODE 2: bf16 out ----
template <int MODE>
__global__ __launch_bounds__(256) void k_mv1024t(
    const float* __restrict__ A, const float* __restrict__ WT, void* __restrict__ Cv)
{
  __shared__ float As[32][34];
  __shared__ float Bs[32][68];
  const int r0 = blockIdx.y * 32;
  const int n0 = blockIdx.x * 64;
  const int tid = threadIdx.x;
  const int tm = tid & 15, tn = tid >> 4;
  float acc[2][4] = {};
  for (int k0 = 0; k0 < 256; k0 += 32) {
    __syncthreads();
    {
      const int m = tid >> 3;
      const int kq = (tid & 7) * 4;
      const float* src = A + (size_t)(r0 + m) * 256 + k0 + kq;
      float4 v = *(const float4*)src;
      As[kq + 0][m] = v.x; As[kq + 1][m] = v.y; As[kq + 2][m] = v.z; As[kq + 3][m] = v.w;
    }
    {
      const int kb = tid >> 3;
      const int nq = (tid & 7) * 8;
      const float* src = WT + (size_t)(k0 + kb) * 1024 + n0 + nq;
      *(float4*)&Bs[kb][nq] = *(const float4*)src;
      *(float4*)&Bs[kb][nq + 4] = *(const float4*)(src + 4);
    }
    __syncthreads();
#pragma unroll
    for (int k = 0; k < 32; ++k) {
      float a0 = As[k][tm * 2 + 0], a1 = As[k][tm * 2 + 1];
      float4 bq = *(const float4*)&Bs[k][tn * 4];
      acc[0][0] += a0 * bq.x; acc[0][1] += a0 * bq.y; acc[0][2] += a0 * bq.z; acc[0][3] += a0 * bq.w;
      acc[1][0] += a1 * bq.x; acc[1][1] += a1 * bq.y; acc[1][2] += a1 * bq.z; acc[1][3] += a1 * bq.w;
    }
  }
#pragma unroll
  for (int i = 0; i < 2; ++i) {
    int r = r0 + tm * 2 + i;
    int j0 = n0 + tn * 4;
    if (MODE == 1) {
      unsigned pk = f32_to_e4m3(acc[i][0]) | (f32_to_e4m3(acc[i][1]) << 8)
                  | (f32_to_e4m3(acc[i][2]) << 16) | (f32_to_e4m3(acc[i][3]) << 24);
      ((unsigned*)Cv)[(size_t)r * 256 + (j0 >> 2)] = pk;
    } else {
      uint2 pk;
      pk.x = f32_bf16(acc[i][0]) | (f32_bf16(acc[i][1]) << 16);
      pk.y = f32_bf16(acc[i][2]) | (f32_bf16(acc[i][3]) << 16);
      *(uint2*)((unsigned short*)Cv + (size_t)r * 1024 + j0) = pk;
    }
  }
}

// ---------------- k_step: ONE dispatch per decode step ----------------
__global__ __launch_bounds__(256) void k_step(
    const unsigned char* __restrict__ egs, const unsigned char* __restrict__ eps,
    const unsigned char* __restrict__ Mbuf, const unsigned char* __restrict__ embp,
    float* __restrict__ ws,
    const float* __restrict__ bq_g, const float* __restrict__ v_g,
    const float* __restrict__ v_p, const float* __restrict__ bq_p,
    float* __restrict__ out_logp, float* __restrict__ out_sels,
    const float* __restrict__ c_in, float* __restrict__ c_out,
    const unsigned char* __restrict__ decp_in, unsigned char* __restrict__ decp_out,
    const unsigned short* __restrict__ whb_in, unsigned short* __restrict__ whb_out,
    int* __restrict__ act_g, int* __restrict__ pos_g,
    const int t)
{
  __shared__ __align__(16) float smem[3264];
  const int blk = blockIdx.x;
  const int tid = threadIdx.x;
  const float* BS = ws + OFF_BSUM;

  if (blk >= 1024) {
    // ======== mv: whb_out tile = h(t)[r0..r0+32) @ WHHT[:, n0..n0+64) ========
    float (*As)[34] = (float(*)[34])smem;
    float (*Bs)[68] = (float(*)[68])(smem + 1088);
    const float* WHHT = ws + OFF_WHHT;
    const int mid = blk - 1024;
    const int r0 = (mid >> 4) * 32;
    const int n0 = (mid & 15) * 64;
    const int tm = tid & 15, tn = tid >> 4;
    float acc[2][4] = {};
    for (int k0 = 0; k0 < 256; k0 += 32) {
      __syncthreads();
      {
        const int m = tid >> 3;
        const int kq = (tid & 7) * 4;
        const int r = r0 + m;
        float4 c4 = *(const float4*)(c_in + (size_t)r * 256 + k0 + kq);
        float cc[4] = {c4.x, c4.y, c4.z, c4.w};
#pragma unroll
        for (int j = 0; j < 4; ++j) {
          int hc = k0 + kq + j;
          unsigned dpu = *(const unsigned*)(decp_in + (size_t)r * 1024 + hc * 4);
          f32x2 d01 = cvt2_fp8(dpu), d23 = cvt2_fp8(dpu >> 16);
          uint2 whu = *(const uint2*)(whb_in + (size_t)r * 1024 + hc * 4);
          float4 bs = *(const float4*)(BS + hc * 4);
          float gi = d01.x + bf16_f32(whu.x & 0xffffu) + bs.x;
          float gf = d01.y + bf16_f32(whu.x >> 16) + bs.y;
          float gg = d23.x + bf16_f32(whu.y & 0xffffu) + bs.z;
          float go = d23.y + bf16_f32(whu.y >> 16) + bs.w;
          float cn = fast_sigm(gf) * cc[j] + fast_sigm(gi) * fast_tanh(gg);
          As[kq + j][m] = fast_sigm(go) * fast_tanh(cn);
        }
      }
      {
        const int kb = tid >> 3;
        const int nq = (tid & 7) * 8;
        const float* src = WHHT + (size_t)(k0 + kb) * 1024 + n0 + nq;
        *(float4*)&Bs[kb][nq] = *(const float4*)src;
        *(float4*)&Bs[kb][nq + 4] = *(const float4*)(src + 4);
      }
      __syncthreads();
#pragma unroll
      for (int k = 0; k < 32; ++k) {
        float a0 = As[k][tm * 2 + 0], a1 = As[k][tm * 2 + 1];
        float4 bq = *(const float4*)&Bs[k][tn * 4];
        acc[0][0] += a0 * bq.x; acc[0][1] += a0 * bq.y; acc[0][2] += a0 * bq.z; acc[0][3] += a0 * bq.w;
        acc[1][0] += a1 * bq.x; acc[1][1] += a1 * bq.y; acc[1][2] += a1 * bq.z; acc[1][3] += a1 * bq.w;
      }
    }
#pragma unroll
    for (int i = 0; i < 2; ++i) {
      int r = r0 + tm * 2 + i;
      int j0 = n0 + tn * 4;
      uint2 pk;
      pk.x = f32_bf16(acc[i][0]) | (f32_bf16(acc[i][1]) << 16);
      pk.y = f32_bf16(acc[i][2]) | (f32_bf16(acc[i][3]) << 16);
      *(uint2*)(whb_out + (size_t)r * 1024 + j0) = pk;
    }
    return;
  }

  // ================= attention part =================
  float* hs    = smem;
  float* qpg_s = smem + 256;
  float* u_s   = smem + 512;
  float* wbuf  = smem + 768;
  float* qpp_s = smem + 1024;
  int*   act_s = (int*)(smem + 1280);   // 200
  float* sred  = smem + 1480;
  float* svals = smem + 1488;
  int*   sidx  = (int*)(smem + 1496);
  int*   pick_p = (int*)(smem + 1504);

  const int b = blk;
  const int lane = tid & 63, wave = tid >> 6;
  const int nact = NS - t;
  float* h_glob = ws + OFF_H;
  const unsigned* WQG2 = (const unsigned*)(ws + OFF_WQG2);

  // pre: LSTM cell for row b
  {
    unsigned dpu = *(const unsigned*)(decp_in + (size_t)b * 1024 + tid * 4);
    f32x2 d01 = cvt2_fp8(dpu), d23 = cvt2_fp8(dpu >> 16);
    uint2 whu = *(const uint2*)(whb_in + (size_t)b * 1024 + tid * 4);
    float4 bs = *(const float4*)(BS + tid * 4);
    float gi = d01.x + bf16_f32(whu.x & 0xffffu) + bs.x;
    float gf = d01.y + bf16_f32(whu.x >> 16) + bs.y;
    float gg = d23.x + bf16_f32(whu.y & 0xffffu) + bs.z;
    float go = d23.y + bf16_f32(whu.y >> 16) + bs.w;
    float cprev = c_in[(size_t)b * 256 + tid];
    float cn = fast_sigm(gf) * cprev + fast_sigm(gi) * fast_tanh(gg);
    float hn = fast_sigm(go) * fast_tanh(cn);
    c_out[(size_t)b * 256 + tid] = cn;
    if (t == NS - 1) h_glob[(size_t)b * 256 + tid] = hn;
    hs[tid] = hn;
    u_s[tid] = NEG_INF;
  }
  if (tid < NS) act_s[tid] = act_g[(size_t)b * NS + tid];
  __syncthreads();

  // P0: qp_g = h.WqTg (half2-packed) + bq_g
  {
    float a0 = 0.f, a1 = 0.f;
#pragma unroll 16
    for (int kk = 0; kk < 128; ++kk) {
      unsigned v = WQG2[kk * 256 + tid];
      __half2 hv = *reinterpret_cast<const __half2*>(&v);
      float2 f = __half22float2(hv);
      a0 = fmaf(hs[2 * kk], f.x, a0);
      a1 = fmaf(hs[2 * kk + 1], f.y, a1);
    }
    qpg_s[tid] = a0 + a1 + bq_g[tid];
  }
  __syncthreads();

  const unsigned char* egb = egs + (size_t)b * (NS * NH);
  const unsigned char* epb = eps + (size_t)b * (NS * NH);

  // P1: glimpse logits over ACTIVE rows (4 waves x 8-row ILP = 32 rows in flight)
  {
    float4 qv; qv.x = qpg_s[lane*4]; qv.y = qpg_s[lane*4+1]; qv.z = qpg_s[lane*4+2]; qv.w = qpg_s[lane*4+3];
    float4 vv = *(const float4*)(v_g + lane * 4);
    int j = wave;
    for (; j + 28 < nact; j += 32) {
      int s[8]; unsigned r[8]; float tt[8];
#pragma unroll
      for (int q = 0; q < 8; ++q) s[q] = act_s[j + q * 4];
#pragma unroll
      for (int q = 0; q < 8; ++q)
        r[q] = *(const unsigned*)(egb + (size_t)s[q] * NH + 4 * lane);
#pragma unroll
      for (int q = 0; q < 8; ++q) tt[q] = row_dot(r[q], qv, vv);
#pragma unroll
      for (int off = 32; off; off >>= 1) {
#pragma unroll
        for (int q = 0; q < 8; ++q) tt[q] += __shfl_xor(tt[q], off);
      }
      if (lane == 0) {
#pragma unroll
        for (int q = 0; q < 8; ++q) u_s[s[q]] = tt[q];
      }
    }
    for (; j + 12 < nact; j += 16) {
      int s0 = act_s[j], s1 = act_s[j + 4], s2 = act_s[j + 8], s3 = act_s[j + 12];
      unsigned r0 = *(const unsigned*)(egb + (size_t)s0 * NH + 4 * lane);
      unsigned r1 = *(const unsigned*)(egb + (size_t)s1 * NH + 4 * lane);
      unsigned r2 = *(const unsigned*)(egb + (size_t)s2 * NH + 4 * lane);
      unsigned r3 = *(const unsigned*)(egb + (size_t)s3 * NH + 4 * lane);
      float t0 = row_dot(r0, qv, vv), t1 = row_dot(r1, qv, vv);
      float t2 = row_dot(r2, qv, vv), t3 = row_dot(r3, qv, vv);
#pragma unroll
      for (int off = 32; off; off >>= 1) {
        t0 += __shfl_xor(t0, off); t1 += __shfl_xor(t1, off);
        t2 += __shfl_xor(t2, off); t3 += __shfl_xor(t3, off);
      }
      if (lane == 0) { u_s[s0] = t0; u_s[s1] = t1; u_s[s2] = t2; u_s[s3] = t3; }
    }
    for (; j < nact; j += 4) {
      int s0 = act_s[j];
      unsigned r0 = *(const unsigned*)(egb + (size_t)s0 * NH + 4 * lane);
      float t0 = row_dot(r0, qv, vv);
#pragma unroll
      for (int off = 32; off; off >>= 1) t0 += __shfl_xor(t0, off);
      if (lane == 0) u_s[s0] = t0;
    }
  }
  __syncthreads();

  // P2: softmax -> wbuf
  {
    float uv = (tid < NS) ? u_s[tid] : NEG_INF;
    float m = uv;
#pragma unroll
    for (int off = 32; off; off >>= 1) m = fmaxf(m, __shfl_xor(m, off));
    if (lane == 0) sred[wave] = m;
    __syncthreads();
    m = fmaxf(fmaxf(sred[0], sred[1]), fmaxf(sred[2], sred[3]));
    float ex = (uv == NEG_INF) ? 0.0f : fast_expn(uv - m);
    float sm = ex;
#pragma unroll
    for (int off = 32; off; off >>= 1) sm += __shfl_xor(sm, off);
    __syncthreads();
    if (lane == 0) sred[wave] = sm;
    __syncthreads();
    float Z = ((sred[0] + sred[1]) + sred[2]) + sred[3];
    wbuf[tid] = ex * fast_rcp(Z);
  }
  __syncthreads();

  // P3': qp_p = sum over ACTIVE s of w[s]*M[b][s][:] + bq_p (8-way ILP)
  {
    const unsigned char* Mb = Mbuf + (size_t)b * (NS * NH) + tid;
    float a0 = 0.f, a1 = 0.f, a2 = 0.f, a3 = 0.f;
    float a4 = 0.f, a5 = 0.f, a6 = 0.f, a7 = 0.f;
    int j = 0;
    for (; j + 7 < nact; j += 8) {
      int s0 = act_s[j],     s1 = act_s[j + 1], s2 = act_s[j + 2], s3 = act_s[j + 3];
      int s4 = act_s[j + 4], s5 = act_s[j + 5], s6 = act_s[j + 6], s7 = act_s[j + 7];
      float m0 = cvt2_fp8((unsigned)Mb[(size_t)s0 * 256]).x;
      float m1 = cvt2_fp8((unsigned)Mb[(size_t)s1 * 256]).x;
      float m2 = cvt2_fp8((unsigned)Mb[(size_t)s2 * 256]).x;
      float m3 = cvt2_fp8((unsigned)Mb[(size_t)s3 * 256]).x;
      float m4 = cvt2_fp8((unsigned)Mb[(size_t)s4 * 256]).x;
      float m5 = cvt2_fp8((unsigned)Mb[(size_t)s5 * 256]).x;
      float m6 = cvt2_fp8((unsigned)Mb[(size_t)s6 * 256]).x;
      float m7 = cvt2_fp8((unsigned)Mb[(size_t)s7 * 256]).x;
      a0 = fmaf(wbuf[s0], m0, a0); a1 = fmaf(wbuf[s1], m1, a1);
      a2 = fmaf(wbuf[s2], m2, a2); a3 = fmaf(wbuf[s3], m3, a3);
      a4 = fmaf(wbuf[s4], m4, a4); a5 = fmaf(wbuf[s5], m5, a5);
      a6 = fmaf(wbuf[s6], m6, a6); a7 = fmaf(wbuf[s7], m7, a7);
    }
    for (; j < nact; ++j) {
      int s0 = act_s[j];
      a0 = fmaf(wbuf[s0], cvt2_fp8((unsigned)Mb[(size_t)s0 * 256]).x, a0);
    }
    qpp_s[tid] = (((a0 + a1) + (a2 + a3)) + ((a4 + a5) + (a6 + a7))) + bq_p[tid];
  }
  u_s[tid] = NEG_INF;
  __syncthreads();

  // P5: pointer logits over ACTIVE rows (4 waves x 8-row ILP)
  {
    float4 qv; qv.x = qpp_s[lane*4]; qv.y = qpp_s[lane*4+1]; qv.z = qpp_s[lane*4+2]; qv.w = qpp_s[lane*4+3];
    float4 vv = *(const float4*)(v_p + lane * 4);
    int j = wave;
    for (; j + 28 < nact; j += 32) {
      int s[8]; unsigned r[8]; float tt[8];
#pragma unroll
      for (int q = 0; q < 8; ++q) s[q] = act_s[j + q * 4];
#pragma unroll
      for (int q = 0; q < 8; ++q)
        r[q] = *(const unsigned*)(epb + (size_t)s[q] * NH + 4 * lane);
#pragma unroll
      for (int q = 0; q < 8; ++q) tt[q] = row_dot(r[q], qv, vv);
#pragma unroll
      for (int off = 32; off; off >>= 1) {
#pragma unroll
        for (int q = 0; q < 8; ++q) tt[q] += __shfl_xor(tt[q], off);
      }
      if (lane == 0) {
#pragma unroll
        for (int q = 0; q < 8; ++q) u_s[s[q]] = 10.0f * fast_tanh(tt[q]);
      }
    }
    for (; j + 12 < nact; j += 16) {
      int s0 = act_s[j], s1 = act_s[j + 4], s2 = act_s[j + 8], s3 = act_s[j + 12];
      unsigned r0 = *(const unsigned*)(epb + (size_t)s0 * NH + 4 * lane);
      unsigned r1 = *(const unsigned*)(epb + (size_t)s1 * NH + 4 * lane);
      unsigned r2 = *(const unsigned*)(epb + (size_t)s2 * NH + 4 * lane);
      unsigned r3 = *(const unsigned*)(epb + (size_t)s3 * NH + 4 * lane);
      float t0 = row_dot(r0, qv, vv), t1 = row_dot(r1, qv, vv);
      float t2 = row_dot(r2, qv, vv), t3 = row_dot(r3, qv, vv);
#pragma unroll
      for (int off = 32; off; off >>= 1) {
        t0 += __shfl_xor(t0, off); t1 += __shfl_xor(t1, off);
        t2 += __shfl_xor(t2, off); t3 += __shfl_xor(t3, off);
      }
      if (lane == 0) {
        u_s[s0] = 10.0f * fast_tanh(t0); u_s[s1] = 10.0f * fast_tanh(t1);
        u_s[s2] = 10.0f * fast_tanh(t2); u_s[s3] = 10.0f * fast_tanh(t3);
      }
    }
    for (; j < nact; j += 4) {
      int s0 = act_s[j];
      unsigned r0 = *(const unsigned*)(epb + (size_t)s0 * NH + 4 * lane);
      float t0 = row_dot(r0, qv, vv);
#pragma unroll
      for (int off = 32; off; off >>= 1) t0 += __shfl_xor(t0, off);
      if (lane == 0) u_s[s0] = 10.0f * fast_tanh(t0);
    }
  }
  __syncthreads();

  // P6: log_softmax, store, argmax, active-list update, gather embp -> decp_out (fp8 raw)
  {
    float uv = (tid < NS) ? u_s[tid] : NEG_INF;
    float m = uv;
#pragma unroll
    for (int off = 32; off; off >>= 1) m = fmaxf(m, __shfl_xor(m, off));
    if (lane == 0) sred[wave] = m;
    __syncthreads();
    m = fmaxf(fmaxf(sred[0], sred[1]), fmaxf(sred[2], sred[3]));
    float ex = (uv == NEG_INF) ? 0.0f : fast_expn(uv - m);
    float sm = ex;
#pragma unroll
    for (int off = 32; off; off >>= 1) sm += __shfl_xor(sm, off);
    __syncthreads();
    if (lane == 0) sred[wave] = sm;
    __syncthreads();
    float Z = ((sred[0] + sred[1]) + sred[2]) + sred[3];
    float lse = fast_log2(Z) * LN2;
    float lp = (uv - m) - lse;
    if (tid < NS) {
      float lp_store = fmaxf(lp, -3.0e38f);  // -inf -> huge finite (harness nan guard)
      __builtin_nontemporal_store(lp_store,
          &out_logp[(size_t)b * (NS * NS) + (size_t)t * NS + tid]);
    }
    float av = lp; int ai = tid;
#pragma unroll
    for (int off = 32; off; off >>= 1) {
      float ov = __shfl_xor(av, off);
      int oi = __shfl_xor(ai, off);
      if (ov > av || (ov == av && oi < ai)) { av = ov; ai = oi; }
    }
    if (lane == 0) { svals[wave] = av; sidx[wave] = ai; }
    __syncthreads();
    if (tid == 0) {
      float bv = svals[0]; int bi = sidx[0];
      for (int wv = 1; wv < 4; ++wv) {
        if (svals[wv] > bv || (svals[wv] == bv && sidx[wv] < bi)) { bv = svals[wv]; bi = sidx[wv]; }
      }
      *pick_p = bi;
      __builtin_nontemporal_store((float)bi, &out_sels[(size_t)b * NS + t]);
      int j = pos_g[(size_t)b * NS + bi];
      int last = act_g[(size_t)b * NS + (nact - 1)];
      act_g[(size_t)b * NS + j] = last;
      pos_g[(size_t)b * NS + last] = j;
    }
    __syncthreads();
    const int s = *pick_p;
    const unsigned char* er = embp + ((size_t)s * NB + b) * 1024;
    unsigned v = __builtin_nontemporal_load((const unsigned*)(er + tid * 4));
    *(unsigned*)(decp_out + (size_t)b * 1024 + tid * 4) = v;   // raw fp8 (lossless)
  }
}

// ---------------- act/pos init (global, per replay) ----------------
__global__ __launch_bounds__(256) void k_actinit(int* __restrict__ act, int* __restrict__ pos)
{
  int i = blockIdx.x * 256 + threadIdx.x;
  if (i < NB * NS) {
    int s = i % NS;
    act[i] = s; pos[i] = s;
  }
}

// ---------------- final h/c copy ----------------
__global__ __launch_bounds__(256) void k_out_hc(
    const float* __restrict__ h, const float* __restrict__ c, float* __restrict__ out)
{
  int i = blockIdx.x * 256 + threadIdx.x;
  if (i < NB * NH) {
    out[OUT_H + i] = h[i];
    out[OUT_C + i] = c[i];
  }
}

// ---------------- host ----------------
extern "C" void kernel_launch(void* const* d_in, const int* in_sizes, int n_in,
                              void* d_out, int out_size, void* d_ws, size_t ws_size,
                              hipStream_t stream)
{
  const float* dec0   = (const float*)d_in[0];
  const float* emb    = (const float*)d_in[1];
  const float* h0     = (const float*)d_in[2];
  const float* c0     = (const float*)d_in[3];
  const float* ctx    = (const float*)d_in[4];
  const float* W_ih   = (const float*)d_in[5];
  const float* W_hh   = (const float*)d_in[6];
  const float* b_ih   = (const float*)d_in[7];
  const float* b_hh   = (const float*)d_in[8];
  const float* Wq_g   = (const float*)d_in[9];
  const float* bq_g   = (const float*)d_in[10];
  const float* Wref_g = (const float*)d_in[11];
  const float* bref_g = (const float*)d_in[12];
  const float* v_g    = (const float*)d_in[13];
  const float* Wq_p   = (const float*)d_in[14];
  const float* bq_p   = (const float*)d_in[15];
  const float* Wref_p = (const float*)d_in[16];
  const float* bref_p = (const float*)d_in[17];
  const float* v_p    = (const float*)d_in[18];

  float* ws = (float*)d_ws;
  float* out = (float*)d_out;
  unsigned char* egs  = (unsigned char*)(ws + OFF_EGS);
  unsigned char* eps  = (unsigned char*)(ws + OFF_EPS);
  unsigned char* embp = (unsigned char*)(ws + OFF_EMBP);
  unsigned char* Mbuf = (unsigned char*)(ws + OFF_M);
  static constexpr size_t OFF_ACT = OFF_BPK_QP + (size_t)32*256*4;
  static constexpr size_t OFF_POS = OFF_ACT + (size_t)NB*NS;
  int* act = (int*)(ws + OFF_ACT);
  int* pos = (int*)(ws + OFF_POS);

  k_init<<<dim3(1024), dim3(256), 0, stream>>>(h0, c0, W_ih, W_hh, b_ih, b_hh,
                                               Wq_g, Wq_p, Wref_g, Wref_p, ws);
  k_actinit<<<dim3((NB * NS + 255) / 256), dim3(256), 0, stream>>>(act, pos);
  k_eproj2<<<dim3(3200), dim3(256), 0, stream>>>(
      ctx, (const bf16x8*)(ws + OFF_BPK_RG), bref_g, egs);
  k_eproj2<<<dim3(3200), dim3(256), 0, stream>>>(
      ctx, (const bf16x8*)(ws + OFF_BPK_RP), bref_p, eps);
  k_embproj2<<<dim3(3200), dim3(256), 0, stream>>>(
      emb, (const bf16x8*)(ws + OFF_BPK_IH), embp);
  k_mproj2<<<dim3(3200), dim3(256), 0, stream>>>(
      egs, (const bf16x8*)(ws + OFF_BPK_QP), Mbuf);
  k_mv1024t<1><<<dim3(16, 32), dim3(256), 0, stream>>>(
      dec0, ws + OFF_WIHT, (void*)(ws + OFF_DECP0));
  k_mv1024t<2><<<dim3(16, 32), dim3(256), 0, stream>>>(
      ws + OFF_H, ws + OFF_WHHT, (void*)(ws + OFF_WHB0));

  for (int t = 0; t < NS; ++t) {
    const int par = t & 1;
    const float* c_in    = ws + (par ? OFF_C1 : OFF_C0);
    float*       c_outp  = ws + (par ? OFF_C0 : OFF_C1);
    const unsigned char* decp_in = (const unsigned char*)(ws + (par ? OFF_DECP1 : OFF_DECP0));
    unsigned char*       decp_o  = (unsigned char*)(ws + (par ? OFF_DECP0 : OFF_DECP1));
    const unsigned short* whb_in = (const unsigned short*)(ws + (par ? OFF_WHB1 : OFF_WHB0));
    unsigned short*       whb_o  = (unsigned short*)(ws + (par ? OFF_WHB0 : OFF_WHB1));
    k_step<<<dim3(1536), dim3(256), 0, stream>>>(
        egs, eps, Mbuf, embp, ws, bq_g, v_g, v_p, bq_p,
        out, out + OUT_SELS,
        c_in, c_outp, decp_in, decp_o, whb_in, whb_o, act, pos, t);
  }
  // t=199 (odd): final c in OFF_C0; h in OFF_H
  k_out_hc<<<dim3(1024), dim3(256), 0, stream>>>(ws + OFF_H, ws + OFF_C0, out);
}

// Round 18
// 10790.581 us; speedup vs baseline: 15.3481x; 1.0069x over previous
//
#include <hip/hip_runtime.h>
#include <hip/hip_fp16.h>

// Problem sizes
static constexpr int NB = 1024;   // batch
static constexpr int NS = 200;    // seq len
static constexpr int NH = 256;    // hidden == embed
static constexpr int NG4 = 1024;  // 4*H

#define NEG_INF (-__builtin_inff())
static constexpr float LOG2E = 1.4426950408889634f;
static constexpr float LN2   = 0.6931471805599453f;

// ---------------- workspace layout (float offsets) ----------------
static constexpr size_t OFF_EGS   = 0;                                    // fp8 [B][200][256]
static constexpr size_t OFF_EPS   = OFF_EGS  + (size_t)NB*NS*NH/4;        // fp8 [B][200][256]
static constexpr size_t OFF_EMBP  = OFF_EPS  + (size_t)NB*NS*NH/4;        // fp8 [S][B][1024] emb@WihT
static constexpr size_t OFF_M     = OFF_EMBP + (size_t)NS*NB*NG4/4;       // fp8 [B][200][256] eg@WqpT
static constexpr size_t OFF_WIHT  = OFF_M    + (size_t)NB*NS*NH/4;        // f32 [256][1024] gate-interleaved
static constexpr size_t OFF_WHHT  = OFF_WIHT + (size_t)NH*NG4;            // f32 [256][1024]
static constexpr size_t OFF_BSUM  = OFF_WHHT + (size_t)NH*NG4;            // f32 [1024]
static constexpr size_t OFF_WQG2  = OFF_BSUM + 1024;                      // half2-packed WqTg [128][256]
static constexpr size_t OFF_H     = OFF_WQG2 + (size_t)128*256;           // f32 [B][256]
static constexpr size_t OFF_C0    = OFF_H    + (size_t)NB*NH;             // c parity (f32)
static constexpr size_t OFF_C1    = OFF_C0   + (size_t)NB*NH;
static constexpr size_t OFF_DECP0 = OFF_C1   + (size_t)NB*NH;             // decp parity: fp8 [B][1024]
static constexpr size_t OFF_DECP1 = OFF_DECP0 + (size_t)NB*NG4/4;
static constexpr size_t OFF_WHB0  = OFF_DECP1 + (size_t)NB*NG4/4;         // whb parity: bf16 [B][1024]
static constexpr size_t OFF_WHB1  = OFF_WHB0 + (size_t)NB*NG4/2;
// bf16x8-packed B fragments
static constexpr size_t OFF_BPK_IH = OFF_WHB1 + (size_t)NB*NG4/2;         // [32][1024] x 16B
static constexpr size_t OFF_BPK_RG = OFF_BPK_IH + (size_t)32*1024*4;      // [32][256] x 16B
static constexpr size_t OFF_BPK_RP = OFF_BPK_RG + (size_t)32*256*4;
static constexpr size_t OFF_BPK_QP = OFF_BPK_RP + (size_t)32*256*4;

// ---------------- output layout (float offsets) ----------------
static constexpr size_t OUT_SELS = (size_t)NB*NS*NS;   // log_p first
static constexpr size_t OUT_H    = OUT_SELS + (size_t)NB*NS;
static constexpr size_t OUT_C    = OUT_H + (size_t)NB*NH;

// ---------------- types / fast math ----------------
typedef float f32x2 __attribute__((ext_vector_type(2)));
typedef float f32x4 __attribute__((ext_vector_type(4)));
typedef short bf16x8 __attribute__((ext_vector_type(8)));   // 8 bf16 in 4 VGPRs

__device__ __forceinline__ float fast_exp2(float x) {
  float d; asm("v_exp_f32 %0, %1" : "=v"(d) : "v"(x)); return d;
}
__device__ __forceinline__ float fast_rcp(float x) {
  float d; asm("v_rcp_f32 %0, %1" : "=v"(d) : "v"(x)); return d;
}
__device__ __forceinline__ float fast_log2(float x) {
  float d; asm("v_log_f32 %0, %1" : "=v"(d) : "v"(x)); return d;
}
__device__ __forceinline__ float fast_tanh(float x) {
  float e = fast_exp2(x * (2.0f * LOG2E));
  return fmaf(-2.0f, fast_rcp(e + 1.0f), 1.0f);
}
__device__ __forceinline__ float fast_sigm(float x) {
  float e = fast_exp2(x * (-LOG2E));
  return fast_rcp(1.0f + e);
}
__device__ __forceinline__ float fast_expn(float a) {   // exp(a), a<=0 (or -inf -> 0)
  return fast_exp2(a * LOG2E);
}
__device__ __forceinline__ f32x2 cvt2_fp8(unsigned int u) {
  f32x2 d; asm("v_cvt_pk_f32_fp8 %0, %1" : "=v"(d) : "v"(u)); return d;
}
// HW encode: 4 f32 -> 4 fp8 e4m3 bytes (RNE, saturating)
__device__ __forceinline__ unsigned pack4_fp8(float a, float b, float c, float d) {
  unsigned r;
  asm("v_cvt_pk_fp8_f32 %0, %1, %2" : "=v"(r) : "v"(a), "v"(b));
  asm("v_cvt_pk_fp8_f32 %0, %1, %2 op_sel:[0,0,1]" : "+v"(r) : "v"(c), "v"(d));
  return r;
}
// HW encode: 2 f32 -> packed bf16x2 (RNE)
__device__ __forceinline__ unsigned pack2_bf16(float lo, float hi) {
  unsigned r;
  asm("v_cvt_pk_bf16_f32 %0, %1, %2" : "=v"(r) : "v"(lo), "v"(hi));
  return r;
}
// software encode kept for k_init one-time packing
__device__ __forceinline__ unsigned int f32_to_e4m3(float x) {
  x = fminf(fmaxf(x, -448.0f), 448.0f);
  unsigned int u = __float_as_uint(x);
  unsigned int s = (u >> 24) & 0x80u;
  unsigned int au = u & 0x7fffffffu;
  if (au < 0x3c800000u) return s;
  unsigned int r = au + 0x7ffffu + ((au >> 20) & 1u);
  unsigned int expf8 = (r >> 23) - 120u;
  unsigned int man = (r >> 20) & 7u;
  return s | (expf8 << 3) | man;
}
// f32 -> bf16 (RNE) (software; k_init only)
__device__ __forceinline__ unsigned f32_bf16(float x) {
  unsigned u = __float_as_uint(x);
  unsigned r = u + 0x7fffu + ((u >> 16) & 1u);
  return r >> 16;
}
__device__ __forceinline__ float bf16_f32(unsigned u) {   // u = low 16 bits
  return __uint_as_float(u << 16);
}

// logits helper: one e-row dot (4 tanh terms) given packed fp8 row word
__device__ __forceinline__ float row_dot(unsigned r, float4 qv, float4 vv) {
  f32x2 lo = cvt2_fp8(r), hi = cvt2_fp8(r >> 16);
  float t = vv.x * fast_tanh(lo.x + qv.x);
  t = fmaf(vv.y, fast_tanh(lo.y + qv.y), t);
  t = fmaf(vv.z, fast_tanh(hi.x + qv.z), t);
  t = fmaf(vv.w, fast_tanh(hi.y + qv.w), t);
  return t;
}

// ---------------- init: weight transforms + bf16 fragment packing ----------------
__global__ __launch_bounds__(256) void k_init(
    const float* __restrict__ h0, const float* __restrict__ c0,
    const float* __restrict__ W_ih, const float* __restrict__ W_hh,
    const float* __restrict__ b_ih, const float* __restrict__ b_hh,
    const float* __restrict__ Wq_g, const float* __restrict__ Wq_p,
    const float* __restrict__ Wref_g, const float* __restrict__ Wref_p,
    float* __restrict__ ws)
{
  const int i0 = blockIdx.x * 256 + threadIdx.x;
  const int stride = gridDim.x * 256;
  float* WIHT = ws + OFF_WIHT;
  float* WHHT = ws + OFF_WHHT;
  float* BS   = ws + OFF_BSUM;
  unsigned* WQG2 = (unsigned*)(ws + OFF_WQG2);
  for (int t = i0; t < NH * NG4; t += stride) {
    int k = t >> 10, j = t & 1023;
    int row = (j & 3) * 256 + (j >> 2);
    WIHT[t] = W_ih[row * NH + k];
    WHHT[t] = W_hh[row * NH + k];
  }
  for (int t = i0; t < 1024; t += stride) {
    int row = (t & 3) * 256 + (t >> 2);
    BS[t] = b_ih[row] + b_hh[row];
  }
  for (int t = i0; t < 128 * 256; t += stride) {
    int kk = t >> 8, o = t & 255;
    __half lo = __float2half(Wq_g[o * NH + 2 * kk]);
    __half hi = __float2half(Wq_g[o * NH + 2 * kk + 1]);
    unsigned v = ((unsigned)__half_as_ushort(hi) << 16) | (unsigned)__half_as_ushort(lo);
    WQG2[t] = v;
  }
  {
    uint4* BP = (uint4*)(ws + OFF_BPK_IH);
    for (int t = i0; t < 32 * 1024; t += stride) {
      int kg = t >> 10, n = t & 1023;
      int row = (n & 3) * 256 + (n >> 2);
      unsigned us[8];
#pragma unroll
      for (int j = 0; j < 8; ++j) us[j] = f32_bf16(W_ih[row * NH + kg * 8 + j]) & 0xffffu;
      BP[t] = (uint4){ us[0]|(us[1]<<16), us[2]|(us[3]<<16), us[4]|(us[5]<<16), us[6]|(us[7]<<16) };
    }
  }
  {
    uint4* BG = (uint4*)(ws + OFF_BPK_RG);
    uint4* BR = (uint4*)(ws + OFF_BPK_RP);
    uint4* BQ = (uint4*)(ws + OFF_BPK_QP);
    for (int t = i0; t < 32 * 256; t += stride) {
      int kg = t >> 8, n = t & 255;
      unsigned g[8], r[8], q[8];
#pragma unroll
      for (int j = 0; j < 8; ++j) {
        int k = kg * 8 + j;
        g[j] = f32_bf16(Wref_g[n * NH + k]) & 0xffffu;
        r[j] = f32_bf16(Wref_p[n * NH + k]) & 0xffffu;
        q[j] = f32_bf16(Wq_p[n * NH + k]) & 0xffffu;
      }
      BG[t] = (uint4){ g[0]|(g[1]<<16), g[2]|(g[3]<<16), g[4]|(g[5]<<16), g[6]|(g[7]<<16) };
      BR[t] = (uint4){ r[0]|(r[1]<<16), r[2]|(r[3]<<16), r[4]|(r[5]<<16), r[6]|(r[7]<<16) };
      BQ[t] = (uint4){ q[0]|(q[1]<<16), q[2]|(q[3]<<16), q[4]|(q[5]<<16), q[6]|(q[7]<<16) };
    }
  }
  float* hbuf = ws + OFF_H;
  float* cbuf = ws + OFF_C0;
  for (int t = i0; t < NB * NH; t += stride) {
    hbuf[t] = h0[t]; cbuf[t] = c0[t];
  }
}

// ---------------- MFMA proj kernels: 64 rows x ALL cols per block ----------------
__global__ __launch_bounds__(256) void k_embproj2(
    const float* __restrict__ A, const bf16x8* __restrict__ Bpk,
    unsigned char* __restrict__ C)
{
  __shared__ unsigned short As16[64][264];
  __shared__ float CtW[4][16][20];
  const int tid = threadIdx.x, l = tid & 63, w = tid >> 6;
  const int r0 = blockIdx.x * 64;
#pragma unroll
  for (int q = 0; q < 16; ++q) {
    int idx = q * 256 + tid;
    int row = idx >> 6, c4 = (idx & 63) * 4;
    float4 v = *(const float4*)(A + (size_t)(r0 + row) * 256 + c4);
    *(unsigned*)&As16[row][c4]     = pack2_bf16(v.x, v.y);
    *(unsigned*)&As16[row][c4 + 2] = pack2_bf16(v.z, v.w);
  }
  __syncthreads();
  const int arow = w * 16 + (l & 15);
  const int kg0 = l >> 4;
  bf16x8 afr[8];
#pragma unroll
  for (int kc = 0; kc < 8; ++kc)
    afr[kc] = *(const bf16x8*)&As16[arow][kc * 32 + kg0 * 8];
  for (int ct = 0; ct < 64; ++ct) {
    f32x4 acc = {};
    const bf16x8* bp = Bpk + ct * 16 + (l & 15);
#pragma unroll
    for (int kc = 0; kc < 8; ++kc)
      acc = __builtin_amdgcn_mfma_f32_16x16x32_bf16(afr[kc], bp[(size_t)(kc * 4 + kg0) * 1024], acc, 0, 0, 0);
#pragma unroll
    for (int r = 0; r < 4; ++r) CtW[w][(l >> 4) * 4 + r][l & 15] = acc[r];
    float4 cv = *(const float4*)&CtW[w][l >> 2][(l & 3) * 4];
    unsigned pk = pack4_fp8(cv.x, cv.y, cv.z, cv.w);
    *(unsigned*)(C + (size_t)(r0 + w * 16 + (l >> 2)) * 1024 + ct * 16 + (l & 3) * 4) = pk;
  }
}

__global__ __launch_bounds__(256) void k_eproj2(
    const float* __restrict__ A, const bf16x8* __restrict__ Bpk,
    const float* __restrict__ bias, unsigned char* __restrict__ C)
{
  __shared__ unsigned short As16[64][264];
  __shared__ float CtW[4][16][20];
  __shared__ float bias_s[256];
  const int tid = threadIdx.x, l = tid & 63, w = tid >> 6;
  const int r0 = blockIdx.x * 64;
  bias_s[tid] = bias[tid];
#pragma unroll
  for (int q = 0; q < 16; ++q) {
    int idx = q * 256 + tid;
    int row = idx >> 6, c4 = (idx & 63) * 4;
    float4 v = *(const float4*)(A + (size_t)(r0 + row) * 256 + c4);
    *(unsigned*)&As16[row][c4]     = pack2_bf16(v.x, v.y);
    *(unsigned*)&As16[row][c4 + 2] = pack2_bf16(v.z, v.w);
  }
  __syncthreads();
  const int arow = w * 16 + (l & 15);
  const int kg0 = l >> 4;
  bf16x8 afr[8];
#pragma unroll
  for (int kc = 0; kc < 8; ++kc)
    afr[kc] = *(const bf16x8*)&As16[arow][kc * 32 + kg0 * 8];
  const int R = r0 + w * 16 + (l >> 2);
  const int b = R & 1023, s = R >> 10;
  for (int ct = 0; ct < 16; ++ct) {
    f32x4 acc = {};
    const bf16x8* bp = Bpk + ct * 16 + (l & 15);
#pragma unroll
    for (int kc = 0; kc < 8; ++kc)
      acc = __builtin_amdgcn_mfma_f32_16x16x32_bf16(afr[kc], bp[(size_t)(kc * 4 + kg0) * 256], acc, 0, 0, 0);
#pragma unroll
    for (int r = 0; r < 4; ++r) CtW[w][(l >> 4) * 4 + r][l & 15] = acc[r];
    float4 cv = *(const float4*)&CtW[w][l >> 2][(l & 3) * 4];
    int cb = ct * 16 + (l & 3) * 4;
    unsigned pk = pack4_fp8(cv.x + bias_s[cb], cv.y + bias_s[cb + 1],
                            cv.z + bias_s[cb + 2], cv.w + bias_s[cb + 3]);
    *(unsigned*)(C + (size_t)b * (NS * NH) + (size_t)s * NH + cb) = pk;
  }
}

__global__ __launch_bounds__(256) void k_mproj2(
    const unsigned char* __restrict__ A, const bf16x8* __restrict__ Bpk,
    unsigned char* __restrict__ C)
{
  __shared__ unsigned short As16[64][264];
  __shared__ float CtW[4][16][20];
  const int tid = threadIdx.x, l = tid & 63, w = tid >> 6;
  const int r0 = blockIdx.x * 64;
#pragma unroll
  for (int q = 0; q < 16; ++q) {
    int idx = q * 256 + tid;
    int row = idx >> 6, c4 = (idx & 63) * 4;
    unsigned v = *(const unsigned*)(A + (size_t)(r0 + row) * 256 + c4);
    f32x2 lo = cvt2_fp8(v), hi = cvt2_fp8(v >> 16);
    *(unsigned*)&As16[row][c4]     = pack2_bf16(lo.x, lo.y);
    *(unsigned*)&As16[row][c4 + 2] = pack2_bf16(hi.x, hi.y);
  }
  __syncthreads();
  const int arow = w * 16 + (l & 15);
  const int kg0 = l >> 4;
  bf16x8 afr[8];
#pragma unroll
  for (int kc = 0; kc < 8; ++kc)
    afr[kc] = *(const bf16x8*)&As16[arow][kc * 32 + kg0 * 8];
  for (int ct = 0; ct < 16; ++ct) {
    f32x4 acc = {};
    const bf16x8* bp = Bpk + ct * 16 + (l & 15);
#pragma unroll
    for (int kc = 0; kc < 8; ++kc)
      acc = __builtin_amdgcn_mfma_f32_16x16x32_bf16(afr[kc], bp[(size_t)(kc * 4 + kg0) * 256], acc, 0, 0, 0);
#pragma unroll
    for (int r = 0; r < 4; ++r) CtW[w][(l >> 4) * 4 + r][l & 15] = acc[r];
    float4 cv = *(const float4*)&CtW[w][l >> 2][(l & 3) * 4];
    unsigned pk = pack4_fp8(cv.x, cv.y, cv.z, cv.w);
    *(unsigned*)(C + (size_t)(r0 + w * 16 + (l >> 2)) * 256 + ct * 16 + (l & 3) * 4) = pk;
  }
}

// ---------------- [1024x256] @ [256][1024] GEMM; MODE 1: fp8 out, MODE 2: bf16 out ----
template <int MODE>
__global__ __launch_bounds__(256) void k_mv1024t(
    const float* __restrict__ A, const float* __restrict__ WT, void* __restrict__ Cv)
{
  __shared__ float As[32][34];
  __shared__ float Bs[32][68];
  const int r0 = blockIdx.y * 32;
  const int n0 = blockIdx.x * 64;
  const int tid = threadIdx.x;
  const int tm = tid & 15, tn = tid >> 4;
  float acc[2][4] = {};
  for (int k0 = 0; k0 < 256; k0 += 32) {
    __syncthreads();
    {
      const int m = tid >> 3;
      const int kq = (tid & 7) * 4;
      const float* src = A + (size_t)(r0 + m) * 256 + k0 + kq;
      float4 v = *(const float4*)src;
      As[kq + 0][m] = v.x; As[kq + 1][m] = v.y; As[kq + 2][m] = v.z; As[kq + 3][m] = v.w;
    }
    {
      const int kb = tid >> 3;
      const int nq = (tid & 7) * 8;
      const float* src = WT + (size_t)(k0 + kb) * 1024 + n0 + nq;
      *(float4*)&Bs[kb][nq] = *(const float4*)src;
      *(float4*)&Bs[kb][nq + 4] = *(const float4*)(src + 4);
    }
    __syncthreads();
#pragma unroll
    for (int k = 0; k < 32; ++k) {
      float a0 = As[k][tm * 2 + 0], a1 = As[k][tm * 2 + 1];
      float4 bq = *(const float4*)&Bs[k][tn * 4];
      acc[0][0] += a0 * bq.x; acc[0][1] += a0 * bq.y; acc[0][2] += a0 * bq.z; acc[0][3] += a0 * bq.w;
      acc[1][0] += a1 * bq.x; acc[1][1] += a1 * bq.y; acc[1][2] += a1 * bq.z; acc[1][3] += a1 * bq.w;
    }
  }
#pragma unroll
  for (int i = 0; i < 2; ++i) {
    int r = r0 + tm * 2 + i;
    int j0 = n0 + tn * 4;
    if (MODE == 1) {
      unsigned pk = pack4_fp8(acc[i][0], acc[i][1], acc[i][2], acc[i][3]);
      ((unsigned*)Cv)[(size_t)r * 256 + (j0 >> 2)] = pk;
    } else {
      uint2 pk;
      pk.x = pack2_bf16(acc[i][0], acc[i][1]);
      pk.y = pack2_bf16(acc[i][2], acc[i][3]);
      *(uint2*)((unsigned short*)Cv + (size_t)r * 1024 + j0) = pk;
    }
  }
}

// ---------------- k_step: ONE dispatch per decode step ----------------
__global__ __launch_bounds__(256) void k_step(
    const unsigned char* __restrict__ egs, const unsigned char* __restrict__ eps,
    const unsigned char* __restrict__ Mbuf, const unsigned char* __restrict__ embp,
    float* __restrict__ ws,
    const float* __restrict__ bq_g, const float* __restrict__ v_g,
    const float* __restrict__ v_p, const float* __restrict__ bq_p,
    float* __restrict__ out_logp, float* __restrict__ out_sels,
    const float* __restrict__ c_in, float* __restrict__ c_out,
    const unsigned char* __restrict__ decp_in, unsigned char* __restrict__ decp_out,
    const unsigned short* __restrict__ whb_in, unsigned short* __restrict__ whb_out,
    int* __restrict__ act_g, int* __restrict__ pos_g,
    const int t)
{
  __shared__ __align__(16) float smem[3264];
  const int blk = blockIdx.x;
  const int tid = threadIdx.x;
  const float* BS = ws + OFF_BSUM;

  if (blk >= 1024) {
    // ======== mv: whb_out tile = h(t)[r0..r0+32) @ WHHT[:, n0..n0+64) ========
    float (*As)[34] = (float(*)[34])smem;
    float (*Bs)[68] = (float(*)[68])(smem + 1088);
    const float* WHHT = ws + OFF_WHHT;
    const int mid = blk - 1024;
    const int r0 = (mid >> 4) * 32;
    const int n0 = (mid & 15) * 64;
    const int tm = tid & 15, tn = tid >> 4;
    float acc[2][4] = {};
    for (int k0 = 0; k0 < 256; k0 += 32) {
      __syncthreads();
      {
        const int m = tid >> 3;
        const int kq = (tid & 7) * 4;
        const int r = r0 + m;
        float4 c4 = *(const float4*)(c_in + (size_t)r * 256 + k0 + kq);
        float cc[4] = {c4.x, c4.y, c4.z, c4.w};
#pragma unroll
        for (int j = 0; j < 4; ++j) {
          int hc = k0 + kq + j;
          unsigned dpu = *(const unsigned*)(decp_in + (size_t)r * 1024 + hc * 4);
          f32x2 d01 = cvt2_fp8(dpu), d23 = cvt2_fp8(dpu >> 16);
          uint2 whu = *(const uint2*)(whb_in + (size_t)r * 1024 + hc * 4);
          float4 bs = *(const float4*)(BS + hc * 4);
          float gi = d01.x + bf16_f32(whu.x & 0xffffu) + bs.x;
          float gf = d01.y + bf16_f32(whu.x >> 16) + bs.y;
          float gg = d23.x + bf16_f32(whu.y & 0xffffu) + bs.z;
          float go = d23.y + bf16_f32(whu.y >> 16) + bs.w;
          float cn = fast_sigm(gf) * cc[j] + fast_sigm(gi) * fast_tanh(gg);
          As[kq + j][m] = fast_sigm(go) * fast_tanh(cn);
        }
      }
      {
        const int kb = tid >> 3;
        const int nq = (tid & 7) * 8;
        const float* src = WHHT + (size_t)(k0 + kb) * 1024 + n0 + nq;
        *(float4*)&Bs[kb][nq] = *(const float4*)src;
        *(float4*)&Bs[kb][nq + 4] = *(const float4*)(src + 4);
      }
      __syncthreads();
#pragma unroll
      for (int k = 0; k < 32; ++k) {
        float a0 = As[k][tm * 2 + 0], a1 = As[k][tm * 2 + 1];
        float4 bq = *(const float4*)&Bs[k][tn * 4];
        acc[0][0] += a0 * bq.x; acc[0][1] += a0 * bq.y; acc[0][2] += a0 * bq.z; acc[0][3] += a0 * bq.w;
        acc[1][0] += a1 * bq.x; acc[1][1] += a1 * bq.y; acc[1][2] += a1 * bq.z; acc[1][3] += a1 * bq.w;
      }
    }
#pragma unroll
    for (int i = 0; i < 2; ++i) {
      int r = r0 + tm * 2 + i;
      int j0 = n0 + tn * 4;
      uint2 pk;
      pk.x = pack2_bf16(acc[i][0], acc[i][1]);
      pk.y = pack2_bf16(acc[i][2], acc[i][3]);
      *(uint2*)(whb_out + (size_t)r * 1024 + j0) = pk;
    }
    return;
  }

  // ================= attention part =================
  float* hs    = smem;
  float* qpg_s = smem + 256;
  float* u_s   = smem + 512;
  float* wbuf  = smem + 768;
  float* qpp_s = smem + 1024;
  int*   act_s = (int*)(smem + 1280);   // 200
  float* sred  = smem + 1480;
  float* svals = smem + 1488;
  int*   sidx  = (int*)(smem + 1496);
  int*   pick_p = (int*)(smem + 1504);

  const int b = blk;
  const int lane = tid & 63, wave = tid >> 6;
  const int nact = NS - t;
  float* h_glob = ws + OFF_H;
  const unsigned* WQG2 = (const unsigned*)(ws + OFF_WQG2);

  // pre: LSTM cell for row b
  {
    unsigned dpu = *(const unsigned*)(decp_in + (size_t)b * 1024 + tid * 4);
    f32x2 d01 = cvt2_fp8(dpu), d23 = cvt2_fp8(dpu >> 16);
    uint2 whu = *(const uint2*)(whb_in + (size_t)b * 1024 + tid * 4);
    float4 bs = *(const float4*)(BS + tid * 4);
    float gi = d01.x + bf16_f32(whu.x & 0xffffu) + bs.x;
    float gf = d01.y + bf16_f32(whu.x >> 16) + bs.y;
    float gg = d23.x + bf16_f32(whu.y & 0xffffu) + bs.z;
    float go = d23.y + bf16_f32(whu.y >> 16) + bs.w;
    float cprev = c_in[(size_t)b * 256 + tid];
    float cn = fast_sigm(gf) * cprev + fast_sigm(gi) * fast_tanh(gg);
    float hn = fast_sigm(go) * fast_tanh(cn);
    c_out[(size_t)b * 256 + tid] = cn;
    if (t == NS - 1) h_glob[(size_t)b * 256 + tid] = hn;
    hs[tid] = hn;
    u_s[tid] = NEG_INF;
  }
  if (tid < NS) act_s[tid] = act_g[(size_t)b * NS + tid];
  __syncthreads();

  // P0: qp_g = h.WqTg (half2-packed) + bq_g
  {
    float a0 = 0.f, a1 = 0.f;
#pragma unroll 16
    for (int kk = 0; kk < 128; ++kk) {
      unsigned v = WQG2[kk * 256 + tid];
      __half2 hv = *reinterpret_cast<const __half2*>(&v);
      float2 f = __half22float2(hv);
      a0 = fmaf(hs[2 * kk], f.x, a0);
      a1 = fmaf(hs[2 * kk + 1], f.y, a1);
    }
    qpg_s[tid] = a0 + a1 + bq_g[tid];
  }
  __syncthreads();

  const unsigned char* egb = egs + (size_t)b * (NS * NH);
  const unsigned char* epb = eps + (size_t)b * (NS * NH);

  // P1: glimpse logits over ACTIVE rows (4 waves x 8-row ILP = 32 rows in flight)
  {
    float4 qv; qv.x = qpg_s[lane*4]; qv.y = qpg_s[lane*4+1]; qv.z = qpg_s[lane*4+2]; qv.w = qpg_s[lane*4+3];
    float4 vv = *(const float4*)(v_g + lane * 4);
    int j = wave;
    for (; j + 28 < nact; j += 32) {
      int s[8]; unsigned r[8]; float tt[8];
#pragma unroll
      for (int q = 0; q < 8; ++q) s[q] = act_s[j + q * 4];
#pragma unroll
      for (int q = 0; q < 8; ++q)
        r[q] = *(const unsigned*)(egb + (size_t)s[q] * NH + 4 * lane);
#pragma unroll
      for (int q = 0; q < 8; ++q) tt[q] = row_dot(r[q], qv, vv);
#pragma unroll
      for (int off = 32; off; off >>= 1) {
#pragma unroll
        for (int q = 0; q < 8; ++q) tt[q] += __shfl_xor(tt[q], off);
      }
      if (lane == 0) {
#pragma unroll
        for (int q = 0; q < 8; ++q) u_s[s[q]] = tt[q];
      }
    }
    for (; j + 12 < nact; j += 16) {
      int s0 = act_s[j], s1 = act_s[j + 4], s2 = act_s[j + 8], s3 = act_s[j + 12];
      unsigned r0 = *(const unsigned*)(egb + (size_t)s0 * NH + 4 * lane);
      unsigned r1 = *(const unsigned*)(egb + (size_t)s1 * NH + 4 * lane);
      unsigned r2 = *(const unsigned*)(egb + (size_t)s2 * NH + 4 * lane);
      unsigned r3 = *(const unsigned*)(egb + (size_t)s3 * NH + 4 * lane);
      float t0 = row_dot(r0, qv, vv), t1 = row_dot(r1, qv, vv);
      float t2 = row_dot(r2, qv, vv), t3 = row_dot(r3, qv, vv);
#pragma unroll
      for (int off = 32; off; off >>= 1) {
        t0 += __shfl_xor(t0, off); t1 += __shfl_xor(t1, off);
        t2 += __shfl_xor(t2, off); t3 += __shfl_xor(t3, off);
      }
      if (lane == 0) { u_s[s0] = t0; u_s[s1] = t1; u_s[s2] = t2; u_s[s3] = t3; }
    }
    for (; j < nact; j += 4) {
      int s0 = act_s[j];
      unsigned r0 = *(const unsigned*)(egb + (size_t)s0 * NH + 4 * lane);
      float t0 = row_dot(r0, qv, vv);
#pragma unroll
      for (int off = 32; off; off >>= 1) t0 += __shfl_xor(t0, off);
      if (lane == 0) u_s[s0] = t0;
    }
  }
  __syncthreads();

  // P2: softmax -> wbuf
  {
    float uv = (tid < NS) ? u_s[tid] : NEG_INF;
    float m = uv;
#pragma unroll
    for (int off = 32; off; off >>= 1) m = fmaxf(m, __shfl_xor(m, off));
    if (lane == 0) sred[wave] = m;
    __syncthreads();
    m = fmaxf(fmaxf(sred[0], sred[1]), fmaxf(sred[2], sred[3]));
    float ex = (uv == NEG_INF) ? 0.0f : fast_expn(uv - m);
    float sm = ex;
#pragma unroll
    for (int off = 32; off; off >>= 1) sm += __shfl_xor(sm, off);
    __syncthreads();
    if (lane == 0) sred[wave] = sm;
    __syncthreads();
    float Z = ((sred[0] + sred[1]) + sred[2]) + sred[3];
    wbuf[tid] = ex * fast_rcp(Z);
  }
  __syncthreads();

  // P3': qp_p = sum over ACTIVE s of w[s]*M[b][s][:] + bq_p (8-way ILP)
  {
    const unsigned char* Mb = Mbuf + (size_t)b * (NS * NH) + tid;
    float a0 = 0.f, a1 = 0.f, a2 = 0.f, a3 = 0.f;
    float a4 = 0.f, a5 = 0.f, a6 = 0.f, a7 = 0.f;
    int j = 0;
    for (; j + 7 < nact; j += 8) {
      int s0 = act_s[j],     s1 = act_s[j + 1], s2 = act_s[j + 2], s3 = act_s[j + 3];
      int s4 = act_s[j + 4], s5 = act_s[j + 5], s6 = act_s[j + 6], s7 = act_s[j + 7];
      float m0 = cvt2_fp8((unsigned)Mb[(size_t)s0 * 256]).x;
      float m1 = cvt2_fp8((unsigned)Mb[(size_t)s1 * 256]).x;
      float m2 = cvt2_fp8((unsigned)Mb[(size_t)s2 * 256]).x;
      float m3 = cvt2_fp8((unsigned)Mb[(size_t)s3 * 256]).x;
      float m4 = cvt2_fp8((unsigned)Mb[(size_t)s4 * 256]).x;
      float m5 = cvt2_fp8((unsigned)Mb[(size_t)s5 * 256]).x;
      float m6 = cvt2_fp8((unsigned)Mb[(size_t)s6 * 256]).x;
      float m7 = cvt2_fp8((unsigned)Mb[(size_t)s7 * 256]).x;
      a0 = fmaf(wbuf[s0], m0, a0); a1 = fmaf(wbuf[s1], m1, a1);
      a2 = fmaf(wbuf[s2], m2, a2); a3 = fmaf(wbuf[s3], m3, a3);
      a4 = fmaf(wbuf[s4], m4, a4); a5 = fmaf(wbuf[s5], m5, a5);
      a6 = fmaf(wbuf[s6], m6, a6); a7 = fmaf(wbuf[s7], m7, a7);
    }
    for (; j < nact; ++j) {
      int s0 = act_s[j];
      a0 = fmaf(wbuf[s0], cvt2_fp8((unsigned)Mb[(size_t)s0 * 256]).x, a0);
    }
    qpp_s[tid] = (((a0 + a1) + (a2 + a3)) + ((a4 + a5) + (a6 + a7))) + bq_p[tid];
  }
  u_s[tid] = NEG_INF;
  __syncthreads();

  // P5: pointer logits over ACTIVE rows (4 waves x 8-row ILP)
  {
    float4 qv; qv.x = qpp_s[lane*4]; qv.y = qpp_s[lane*4+1]; qv.z = qpp_s[lane*4+2]; qv.w = qpp_s[lane*4+3];
    float4 vv = *(const float4*)(v_p + lane * 4);
    int j = wave;
    for (; j + 28 < nact; j += 32) {
      int s[8]; unsigned r[8]; float tt[8];
#pragma unroll
      for (int q = 0; q < 8; ++q) s[q] = act_s[j + q * 4];
#pragma unroll
      for (int q = 0; q < 8; ++q)
        r[q] = *(const unsigned*)(epb + (size_t)s[q] * NH + 4 * lane);
#pragma unroll
      for (int q = 0; q < 8; ++q) tt[q] = row_dot(r[q], qv, vv);
#pragma unroll
      for (int off = 32; off; off >>= 1) {
#pragma unroll
        for (int q = 0; q < 8; ++q) tt[q] += __shfl_xor(tt[q], off);
      }
      if (lane == 0) {
#pragma unroll
        for (int q = 0; q < 8; ++q) u_s[s[q]] = 10.0f * fast_tanh(tt[q]);
      }
    }
    for (; j + 12 < nact; j += 16) {
      int s0 = act_s[j], s1 = act_s[j + 4], s2 = act_s[j + 8], s3 = act_s[j + 12];
      unsigned r0 = *(const unsigned*)(epb + (size_t)s0 * NH + 4 * lane);
      unsigned r1 = *(const unsigned*)(epb + (size_t)s1 * NH + 4 * lane);
      unsigned r2 = *(const unsigned*)(epb + (size_t)s2 * NH + 4 * lane);
      unsigned r3 = *(const unsigned*)(epb + (size_t)s3 * NH + 4 * lane);
      float t0 = row_dot(r0, qv, vv), t1 = row_dot(r1, qv, vv);
      float t2 = row_dot(r2, qv, vv), t3 = row_dot(r3, qv, vv);
#pragma unroll
      for (int off = 32; off; off >>= 1) {
        t0 += __shfl_xor(t0, off); t1 += __shfl_xor(t1, off);
        t2 += __shfl_xor(t2, off); t3 += __shfl_xor(t3, off);
      }
      if (lane == 0) {
        u_s[s0] = 10.0f * fast_tanh(t0); u_s[s1] = 10.0f * fast_tanh(t1);
        u_s[s2] = 10.0f * fast_tanh(t2); u_s[s3] = 10.0f * fast_tanh(t3);
      }
    }
    for (; j < nact; j += 4) {
      int s0 = act_s[j];
      unsigned r0 = *(const unsigned*)(epb + (size_t)s0 * NH + 4 * lane);
      float t0 = row_dot(r0, qv, vv);
#pragma unroll
      for (int off = 32; off; off >>= 1) t0 += __shfl_xor(t0, off);
      if (lane == 0) u_s[s0] = 10.0f * fast_tanh(t0);
    }
  }
  __syncthreads();

  // P6: log_softmax, store, argmax, active-list update, gather embp -> decp_out (fp8 raw)
  {
    float uv = (tid < NS) ? u_s[tid] : NEG_INF;
    float m = uv;
#pragma unroll
    for (int off = 32; off; off >>= 1) m = fmaxf(m, __shfl_xor(m, off));
    if (lane == 0) sred[wave] = m;
    __syncthreads();
    m = fmaxf(fmaxf(sred[0], sred[1]), fmaxf(sred[2], sred[3]));
    float ex = (uv == NEG_INF) ? 0.0f : fast_expn(uv - m);
    float sm = ex;
#pragma unroll
    for (int off = 32; off; off >>= 1) sm += __shfl_xor(sm, off);
    __syncthreads();
    if (lane == 0) sred[wave] = sm;
    __syncthreads();
    float Z = ((sred[0] + sred[1]) + sred[2]) + sred[3];
    float lse = fast_log2(Z) * LN2;
    float lp = (uv - m) - lse;
    if (tid < NS) {
      float lp_store = fmaxf(lp, -3.0e38f);  // -inf -> huge finite (harness nan guard)
      __builtin_nontemporal_store(lp_store,
          &out_logp[(size_t)b * (NS * NS) + (size_t)t * NS + tid]);
    }
    float av = lp; int ai = tid;
#pragma unroll
    for (int off = 32; off; off >>= 1) {
      float ov = __shfl_xor(av, off);
      int oi = __shfl_xor(ai, off);
      if (ov > av || (ov == av && oi < ai)) { av = ov; ai = oi; }
    }
    if (lane == 0) { svals[wave] = av; sidx[wave] = ai; }
    __syncthreads();
    if (tid == 0) {
      float bv = svals[0]; int bi = sidx[0];
      for (int wv = 1; wv < 4; ++wv) {
        if (svals[wv] > bv || (svals[wv] == bv && sidx[wv] < bi)) { bv = svals[wv]; bi = sidx[wv]; }
      }
      *pick_p = bi;
      __builtin_nontemporal_store((float)bi, &out_sels[(size_t)b * NS + t]);
      int j = pos_g[(size_t)b * NS + bi];
      int last = act_g[(size_t)b * NS + (nact - 1)];
      act_g[(size_t)b * NS + j] = last;
      pos_g[(size_t)b * NS + last] = j;
    }
    __syncthreads();
    const int s = *pick_p;
    const unsigned char* er = embp + ((size_t)s * NB + b) * 1024;
    unsigned v = __builtin_nontemporal_load((const unsigned*)(er + tid * 4));
    *(unsigned*)(decp_out + (size_t)b * 1024 + tid * 4) = v;   // raw fp8 (lossless)
  }
}

// ---------------- act/pos init (global, per replay) ----------------
__global__ __launch_bounds__(256) void k_actinit(int* __restrict__ act, int* __restrict__ pos)
{
  int i = blockIdx.x * 256 + threadIdx.x;
  if (i < NB * NS) {
    int s = i % NS;
    act[i] = s; pos[i] = s;
  }
}

// ---------------- final h/c copy ----------------
__global__ __launch_bounds__(256) void k_out_hc(
    const float* __restrict__ h, const float* __restrict__ c, float* __restrict__ out)
{
  int i = blockIdx.x * 256 + threadIdx.x;
  if (i < NB * NH) {
    out[OUT_H + i] = h[i];
    out[OUT_C + i] = c[i];
  }
}

// ---------------- host ----------------
extern "C" void kernel_launch(void* const* d_in, const int* in_sizes, int n_in,
                              void* d_out, int out_size, void* d_ws, size_t ws_size,
                              hipStream_t stream)
{
  const float* dec0   = (const float*)d_in[0];
  const float* emb    = (const float*)d_in[1];
  const float* h0     = (const float*)d_in[2];
  const float* c0     = (const float*)d_in[3];
  const float* ctx    = (const float*)d_in[4];
  const float* W_ih   = (const float*)d_in[5];
  const float* W_hh   = (const float*)d_in[6];
  const float* b_ih   = (const float*)d_in[7];
  const float* b_hh   = (const float*)d_in[8];
  const float* Wq_g   = (const float*)d_in[9];
  const float* bq_g   = (const float*)d_in[10];
  const float* Wref_g = (const float*)d_in[11];
  const float* bref_g = (const float*)d_in[12];
  const float* v_g    = (const float*)d_in[13];
  const float* Wq_p   = (const float*)d_in[14];
  const float* bq_p   = (const float*)d_in[15];
  const float* Wref_p = (const float*)d_in[16];
  const float* bref_p = (const float*)d_in[17];
  const float* v_p    = (const float*)d_in[18];

  float* ws = (float*)d_ws;
  float* out = (float*)d_out;
  unsigned char* egs  = (unsigned char*)(ws + OFF_EGS);
  unsigned char* eps  = (unsigned char*)(ws + OFF_EPS);
  unsigned char* embp = (unsigned char*)(ws + OFF_EMBP);
  unsigned char* Mbuf = (unsigned char*)(ws + OFF_M);
  static constexpr size_t OFF_ACT = OFF_BPK_QP + (size_t)32*256*4;
  static constexpr size_t OFF_POS = OFF_ACT + (size_t)NB*NS;
  int* act = (int*)(ws + OFF_ACT);
  int* pos = (int*)(ws + OFF_POS);

  k_init<<<dim3(1024), dim3(256), 0, stream>>>(h0, c0, W_ih, W_hh, b_ih, b_hh,
                                               Wq_g, Wq_p, Wref_g, Wref_p, ws);
  k_actinit<<<dim3((NB * NS + 255) / 256), dim3(256), 0, stream>>>(act, pos);
  k_eproj2<<<dim3(3200), dim3(256), 0, stream>>>(
      ctx, (const bf16x8*)(ws + OFF_BPK_RG), bref_g, egs);
  k_eproj2<<<dim3(3200), dim3(256), 0, stream>>>(
      ctx, (const bf16x8*)(ws + OFF_BPK_RP), bref_p, eps);
  k_embproj2<<<dim3(3200), dim3(256), 0, stream>>>(
      emb, (const bf16x8*)(ws + OFF_BPK_IH), embp);
  k_mproj2<<<dim3(3200), dim3(256), 0, stream>>>(
      egs, (const bf16x8*)(ws + OFF_BPK_QP), Mbuf);
  k_mv1024t<1><<<dim3(16, 32), dim3(256), 0, stream>>>(
      dec0, ws + OFF_WIHT, (void*)(ws + OFF_DECP0));
  k_mv1024t<2><<<dim3(16, 32), dim3(256), 0, stream>>>(
      ws + OFF_H, ws + OFF_WHHT, (void*)(ws + OFF_WHB0));

  for (int t = 0; t < NS; ++t) {
    const int par = t & 1;
    const float* c_in    = ws + (par ? OFF_C1 : OFF_C0);
    float*       c_outp  = ws + (par ? OFF_C0 : OFF_C1);
    const unsigned char* decp_in = (const unsigned char*)(ws + (par ? OFF_DECP1 : OFF_DECP0));
    unsigned char*       decp_o  = (unsigned char*)(ws + (par ? OFF_DECP0 : OFF_DECP1));
    const unsigned short* whb_in = (const unsigned short*)(ws + (par ? OFF_WHB1 : OFF_WHB0));
    unsigned short*       whb_o  = (unsigned short*)(ws + (par ? OFF_WHB0 : OFF_WHB1));
    k_step<<<dim3(1536), dim3(256), 0, stream>>>(
        egs, eps, Mbuf, embp, ws, bq_g, v_g, v_p, bq_p,
        out, out + OUT_SELS,
        c_in, c_outp, decp_in, decp_o, whb_in, whb_o, act, pos, t);
  }
  // t=199 (odd): final c in OFF_C0; h in OFF_H
  k_out_hc<<<dim3(1024), dim3(256), 0, stream>>>(ws + OFF_H, ws + OFF_C0, out);
}